// Round 20
// baseline (231.018 us; speedup 1.0000x reference)
//
#include <hip/hip_runtime.h>
#include <math.h>

typedef __attribute__((ext_vector_type(8))) short short8;
typedef __attribute__((ext_vector_type(4))) short short4v;
typedef __attribute__((ext_vector_type(4))) float f32x4;

#define NB 256
#define NVU 64
#define NTU 77
#define PD 512

// ---- d_out offsets (in floats) ----
#define O_VP 3ull
#define O_TP (O_VP + (size_t)NB * NVU * PD)
#define O_VG (O_TP + (size_t)NB * NTU * PD)
#define O_TG (O_VG + (size_t)NB * PD)
#define O_SM (O_TG + (size_t)NB * PD)

// ---- ws offsets (bytes) ----
#define WS_VW1T 0u
#define WS_VW2T 524288u
#define WS_TW1T 1048576u
#define WS_TW2T 1572864u
#define WS_GVWT 2097152u
#define WS_GTWT 2883584u
#define WS_LOG  3552256u
#define WS_DIAG 3814400u
#define WS_RLSE 3815424u
#define WS_CLSE 3816448u
#define WS_UP   3817472u
#define WS_UC   3818496u
#define WS_PART 3819520u   // 512 floats -> ends 3821568
#define WS_TT   3821568u   // t_global^T f32[512][256] = 524288
#define WS_LOGT 4345856u   // logits^T f32[256][256] = 262144

// async global->LDS, 16B per lane; LDS dest = wave-uniform base + lane*16
#define GL_LDS16(gp, lp) __builtin_amdgcn_global_load_lds( \
    (const __attribute__((address_space(1))) void*)(gp), \
    (__attribute__((address_space(3))) void*)(lp), 16, 0, 0)

__device__ inline short f2bf(float f) {
  union { float f; unsigned u; } v; v.f = f;
  unsigned r = v.u + 0x7FFFu + ((v.u >> 16) & 1u);   // RNE
  return (short)(r >> 16);
}
__device__ inline float bf2f(short s) {
  union { unsigned u; float f; } v; v.u = ((unsigned)(unsigned short)s) << 16;
  return v.f;
}

__device__ inline float blk_sum_(float x, float* buf, int nw) {
  const int lane = threadIdx.x & 63, w = threadIdx.x >> 6;
  #pragma unroll
  for (int m = 1; m < 64; m <<= 1) x += __shfl_xor(x, m, 64);
  __syncthreads();
  if (lane == 0) buf[w] = x;
  __syncthreads();
  float s = 0.f;
  for (int i = 0; i < nw; ++i) s += buf[i];
  return s;
}
__device__ inline float blk_max_(float x, float* buf, int nw) {
  const int lane = threadIdx.x & 63, w = threadIdx.x >> 6;
  #pragma unroll
  for (int m = 1; m < 64; m <<= 1) x = fmaxf(x, __shfl_xor(x, m, 64));
  __syncthreads();
  if (lane == 0) buf[w] = x;
  __syncthreads();
  float s = buf[0];
  for (int i = 1; i < nw; ++i) s = fmaxf(s, buf[i]);
  return s;
}

// ---------------- merged prep: unit-weight fragment cvt (bids 0..511) +
//                  global-proj transposes (bids 512..3071) ----------------
__global__ __launch_bounds__(256) void k_prep(
    const float* __restrict__ s0, const float* __restrict__ s1,
    const float* __restrict__ s2, const float* __restrict__ s3,
    short* __restrict__ d0, short* __restrict__ d1,
    short* __restrict__ d2, short* __restrict__ d3,
    const float* __restrict__ gv, short* __restrict__ dv_,
    const float* __restrict__ gt, short* __restrict__ dt_) {
  __shared__ short tile[32][66];
  const int bid = blockIdx.x;
  if (bid < 512) {
    const int m = bid >> 7;
    const float* src = m == 0 ? s0 : m == 1 ? s1 : m == 2 ? s2 : s3;
    short* dst = m == 0 ? d0 : m == 1 ? d1 : m == 2 ? d2 : d3;
    const int rem = bid & 127;
    const int kc = rem >> 3, nt = rem & 7;
    const int n0 = nt * 64;
    #pragma unroll
    for (int it = 0; it < 8; ++it) {
      int idx = it * 256 + threadIdx.x;
      int r = idx >> 6, c = idx & 63;
      tile[r][c] = f2bf(src[(size_t)(kc * 32 + r) * 512 + n0 + c]);
    }
    __syncthreads();
    const int nl = threadIdx.x >> 2, s = threadIdx.x & 3;
    const int n = n0 + nl;
    short8 v;
    #pragma unroll
    for (int j = 0; j < 8; ++j) v[j] = tile[s * 8 + j][nl];
    *(short8*)&dst[(size_t)kc * 16384 + n * 32 + ((s ^ ((n >> 1) & 3)) << 3)] = v;
  } else if (bid < 2048) {
    int idx = (bid - 512) * 256 + threadIdx.x;      // 768*512
    int k = idx >> 9, n = idx & 511;
    dv_[(size_t)n * 768 + k] = f2bf(gv[idx]);
  } else {
    int idx = (bid - 2048) * 256 + threadIdx.x;     // 512*512
    int k = idx >> 9, n = idx & 511;
    dt_[(size_t)n * 512 + k] = f2bf(gt[idx]);
  }
}

// ---------------- mega kernel: mlp+vis-div (0..563) + txt-div (564..691) + gproj (692..1203) ----
__global__ __launch_bounds__(1024) void k_mega(
    const float* __restrict__ Xv, const float* __restrict__ Xt,
    const short* __restrict__ vWf1, const float* __restrict__ vb1,
    const float* __restrict__ vg, const float* __restrict__ vbt,
    const short* __restrict__ vWf2, const float* __restrict__ vb2,
    const short* __restrict__ tWf1, const float* __restrict__ tb1,
    const float* __restrict__ tg, const float* __restrict__ tbt,
    const short* __restrict__ tWf2, const float* __restrict__ tb2,
    float* __restrict__ outV, float* __restrict__ outT,
    const float* __restrict__ vsrc, const float* __restrict__ tsrc,
    const short* __restrict__ gvWT, const float* __restrict__ gvb,
    const float* __restrict__ gvg, const float* __restrict__ gvbt,
    const short* __restrict__ gtWT, const float* __restrict__ gtb,
    const float* __restrict__ gtg, const float* __restrict__ gtbt,
    float* __restrict__ outVG, float* __restrict__ outTG,
    float* __restrict__ Tt, float* __restrict__ part) {
  __shared__ __align__(16) short As[64][520];      // 66560 B
  __shared__ __align__(16) short Bs[2][16384];     // 65536 B
  __shared__ float redS[4][64];
  __shared__ float redQ[4][64];

  const int tid = threadIdx.x;
  const int w = tid >> 6, lane = tid & 63;
  const int hi = lane >> 4, lo = lane & 15;
  const int bid = blockIdx.x;

  if (bid < 564) {
    // ================= unit MLP (r15 structure) + fused vis diversity =================
    const int rg = w >> 2, cg = w & 3;
    // bijective XCD swizzle for 564 = 8*70 + 4 (m204)
    const int xcd = bid & 7, ii = bid >> 3;
    const int orig = (xcd < 4 ? xcd * 71 : 284 + (xcd - 4) * 70) + ii;
    const bool isv = orig < 256;
    const int rb = isv ? orig : orig - 256;
    const float* __restrict__ X   = isv ? Xv : Xt;
    const short* __restrict__ Wf1 = isv ? vWf1 : tWf1;
    const float* __restrict__ b1  = isv ? vb1  : tb1;
    const float* __restrict__ gg  = isv ? vg   : tg;
    const float* __restrict__ bt  = isv ? vbt  : tbt;
    const short* __restrict__ Wf2 = isv ? vWf2 : tWf2;
    const float* __restrict__ b2  = isv ? vb2  : tb2;
    float* __restrict__ outF      = isv ? outV : outT;
    const size_t row0 = (size_t)rb * 64;

    const int arow = rg * 16 + lo;
    const int bswz = (cg * 128 + lo) * 32 + ((hi ^ ((lo >> 1) & 3)) * 8);

    GL_LDS16(Wf1 + tid * 8, &Bs[0][tid * 8]);
    GL_LDS16(Wf1 + 8192 + tid * 8, &Bs[0][8192 + tid * 8]);

    const f32x4* Xp = (const f32x4*)(X + row0 * 512);
    #pragma unroll
    for (int i = 0; i < 8; ++i) {
      int idx = i * 1024 + tid;
      f32x4 f = __builtin_nontemporal_load(Xp + idx);
      short4v s4 = {f2bf(f[0]), f2bf(f[1]), f2bf(f[2]), f2bf(f[3])};
      *(short4v*)&As[idx >> 7][(idx & 127) * 4] = s4;
    }
    __syncthreads();   // X + W1 chunk 0 resident

    // issue W1 chunk 1 (2 in flight)
    GL_LDS16(Wf1 + 16384 + tid * 8, &Bs[1][tid * 8]);
    GL_LDS16(Wf1 + 16384 + 8192 + tid * 8, &Bs[1][8192 + tid * 8]);

    if (isv) {
      // ---- fused vis-diversity gram on raw X tile (batch rb == 64 rows) ----
      // wave w computes 16x16 gram tile (ti, tj); C layout: row=hi*4+r, col=lo (m89)
      const int ti = rg, tj = cg;
      f32x4 g = (f32x4){0.f, 0.f, 0.f, 0.f};
      for (int kc = 0; kc < 16; ++kc) {
        short8 ga = *(const short8*)&As[ti * 16 + lo][kc * 32 + hi * 8];
        short8 gb = *(const short8*)&As[tj * 16 + lo][kc * 32 + hi * 8];
        g = __builtin_amdgcn_mfma_f32_16x16x32_bf16(ga, gb, g, 0, 0, 0);
      }
      float* invs = &redQ[0][0];          // 64 floats (redQ free until GEMM1 epilogue)
      if (ti == tj && (lo >> 2) == hi)
        invs[ti * 16 + lo] = 1.f / fmaxf(sqrtf(fmaxf(g[lo & 3], 0.f)), 1e-12f);
      __syncthreads();
      float cs = 0.f;
      #pragma unroll
      for (int r = 0; r < 4; ++r) {
        int i = ti * 16 + hi * 4 + r, j = tj * 16 + lo;
        if (i != j) cs += fabsf(g[r]) * invs[i] * invs[j];
      }
      #pragma unroll
      for (int m = 1; m < 64; m <<= 1) cs += __shfl_xor(cs, m, 64);
      if (lane == 0) redS[0][w] = cs;
      __syncthreads();
      if (tid == 0) {
        float s = 0.f;
        #pragma unroll
        for (int i = 0; i < 16; ++i) s += redS[0][i];
        part[rb] = s;
      }
    }

    f32x4 acc[8];
    #pragma unroll
    for (int ct = 0; ct < 8; ++ct) acc[ct] = (f32x4){0.f, 0.f, 0.f, 0.f};

    for (int kc = 0; kc < 16; ++kc) {
      const int cur = kc & 1;
      short8 a = *(const short8*)&As[arow][kc * 32 + hi * 8];
      #pragma unroll
      for (int ct = 0; ct < 8; ++ct) {
        short8 bb = *(const short8*)&Bs[cur][bswz + ct * 512];
        acc[ct] = __builtin_amdgcn_mfma_f32_16x16x32_bf16(a, bb, acc[ct], 0, 0, 0);
      }
      __builtin_amdgcn_s_barrier();
      const int nc = kc + 2;
      const short* nxt = (nc < 16) ? (Wf1 + (size_t)nc * 16384)
                                   : (Wf2 + (size_t)(nc - 16) * 16384);
      GL_LDS16(nxt + tid * 8, &Bs[cur][tid * 8]);
      GL_LDS16(nxt + 8192 + tid * 8, &Bs[cur][8192 + tid * 8]);
      asm volatile("s_waitcnt vmcnt(2)" ::: "memory");
    }

    {
      float ps[4] = {0.f, 0.f, 0.f, 0.f}, pq[4] = {0.f, 0.f, 0.f, 0.f};
      #pragma unroll
      for (int ct = 0; ct < 8; ++ct) {
        float bia = b1[cg * 128 + ct * 16 + lo];
        #pragma unroll
        for (int r = 0; r < 4; ++r) {
          float v = acc[ct][r] + bia;
          acc[ct][r] = v;
          ps[r] += v; pq[r] += v * v;
        }
      }
      #pragma unroll
      for (int m = 1; m < 16; m <<= 1)
        #pragma unroll
        for (int r = 0; r < 4; ++r) {
          ps[r] += __shfl_xor(ps[r], m, 64);
          pq[r] += __shfl_xor(pq[r], m, 64);
        }
      if (lo == 0) {
        #pragma unroll
        for (int r = 0; r < 4; ++r) {
          int rr = rg * 16 + hi * 4 + r;
          redS[cg][rr] = ps[r]; redQ[cg][rr] = pq[r];
        }
      }
    }
    __syncthreads();

    {
      float mu[4], rs[4];
      #pragma unroll
      for (int r = 0; r < 4; ++r) {
        int rr = rg * 16 + hi * 4 + r;
        float s = redS[0][rr] + redS[1][rr] + redS[2][rr] + redS[3][rr];
        float q = redQ[0][rr] + redQ[1][rr] + redQ[2][rr] + redQ[3][rr];
        float m_ = s * (1.f / 512.f);
        mu[r] = m_;
        rs[r] = rsqrtf(q * (1.f / 512.f) - m_ * m_ + 1e-5f);
      }
      #pragma unroll
      for (int ct = 0; ct < 8; ++ct) {
        int col = cg * 128 + ct * 16 + lo;
        float ga = gg[col], be = bt[col];
        #pragma unroll
        for (int r = 0; r < 4; ++r) {
          float xn = (acc[ct][r] - mu[r]) * rs[r] * ga + be;
          float ge = 0.5f * xn * (1.f + erff(xn * 0.70710678118654752f));
          As[rg * 16 + hi * 4 + r][col] = f2bf(ge);
        }
      }
    }
    __syncthreads();

    #pragma unroll
    for (int ct = 0; ct < 8; ++ct) acc[ct] = (f32x4){0.f, 0.f, 0.f, 0.f};
    for (int kc = 0; kc < 16; ++kc) {
      const int cur = kc & 1;
      short8 a = *(const short8*)&As[arow][kc * 32 + hi * 8];
      #pragma unroll
      for (int ct = 0; ct < 8; ++ct) {
        short8 bb = *(const short8*)&Bs[cur][bswz + ct * 512];
        acc[ct] = __builtin_amdgcn_mfma_f32_16x16x32_bf16(a, bb, acc[ct], 0, 0, 0);
      }
      __builtin_amdgcn_s_barrier();
      if (kc < 14) {
        const short* nxt = Wf2 + (size_t)(kc + 2) * 16384;
        GL_LDS16(nxt + tid * 8, &Bs[cur][tid * 8]);
        GL_LDS16(nxt + 8192 + tid * 8, &Bs[cur][8192 + tid * 8]);
        asm volatile("s_waitcnt vmcnt(2)" ::: "memory");
      } else if (kc == 14) {
        asm volatile("s_waitcnt vmcnt(0)" ::: "memory");
      }
    }

    {
      float pq[4] = {0.f, 0.f, 0.f, 0.f};
      #pragma unroll
      for (int ct = 0; ct < 8; ++ct) {
        float bia = b2[cg * 128 + ct * 16 + lo];
        #pragma unroll
        for (int r = 0; r < 4; ++r) {
          float v = acc[ct][r] + bia;
          acc[ct][r] = v;
          pq[r] += v * v;
        }
      }
      #pragma unroll
      for (int m = 1; m < 16; m <<= 1)
        #pragma unroll
        for (int r = 0; r < 4; ++r) pq[r] += __shfl_xor(pq[r], m, 64);
      if (lo == 0) {
        #pragma unroll
        for (int r = 0; r < 4; ++r) redQ[cg][rg * 16 + hi * 4 + r] = pq[r];
      }
    }
    __syncthreads();
    {
      float invn[4];
      #pragma unroll
      for (int r = 0; r < 4; ++r) {
        int rr = rg * 16 + hi * 4 + r;
        float q = redQ[0][rr] + redQ[1][rr] + redQ[2][rr] + redQ[3][rr];
        invn[r] = 1.f / fmaxf(sqrtf(q), 1e-12f);
      }
      #pragma unroll
      for (int ct = 0; ct < 8; ++ct) {
        int col = cg * 128 + ct * 16 + lo;
        #pragma unroll
        for (int r = 0; r < 4; ++r)
          outF[(row0 + rg * 16 + hi * 4 + r) * 512 + col] = acc[ct][r] * invn[r];
      }
    }
  } else if (bid < 692) {
    // ================= txt diversity (2 batches per block; tid<320 for MFMA) ========
    short (*Bsd)[136] = (short(*)[136])&As[0][0];   // 80*136*2 = 21760 B
    float* invs = &redQ[0][0];                       // 80 floats
    float* rbuf5 = &redS[0][0];                      // 5 floats
    const int ri = w * 16 + lo;
    for (int half = 0; half < 2; ++half) {
      const int b = (bid - 564) * 2 + half;          // 0..255
      const float* X = Xt + (size_t)b * NTU * 512;
      f32x4 acc[5];
      #pragma unroll
      for (int ct = 0; ct < 5; ++ct) acc[ct] = (f32x4){0.f, 0.f, 0.f, 0.f};

      for (int c = 0; c < 4; ++c) {
        for (int s5 = tid; s5 < 80 * 32; s5 += 1024) {
          int r = s5 >> 5, cgp = s5 & 31;
          short4v s4 = {0, 0, 0, 0};
          if (r < NTU) {
            float4 f = *(const float4*)(X + (size_t)r * 512 + c * 128 + cgp * 4);
            s4 = (short4v){f2bf(f.x), f2bf(f.y), f2bf(f.z), f2bf(f.w)};
          }
          *(short4v*)&Bsd[r][cgp * 4] = s4;
        }
        __syncthreads();
        if (tid < 320) {
          #pragma unroll
          for (int kc = 0; kc < 4; ++kc) {
            short8 a = *(const short8*)&Bsd[ri][kc * 32 + hi * 8];
            #pragma unroll
            for (int ct = 0; ct < 5; ++ct) {
              short8 bb = *(const short8*)&Bsd[ct * 16 + lo][kc * 32 + hi * 8];
              acc[ct] = __builtin_amdgcn_mfma_f32_16x16x32_bf16(a, bb, acc[ct], 0, 0, 0);
            }
          }
        }
        __syncthreads();
      }

      if (tid < 320) {
        #pragma unroll
        for (int ct = 0; ct < 5; ++ct)
          #pragma unroll
          for (int r = 0; r < 4; ++r) {
            int i = w * 16 + hi * 4 + r, j = ct * 16 + lo;
            if (i == j && i < NTU) invs[i] = 1.f / fmaxf(sqrtf(fmaxf(acc[ct][r], 0.f)), 1e-12f);
          }
      }
      __syncthreads();

      float cs = 0.f;
      if (tid < 320) {
        #pragma unroll
        for (int ct = 0; ct < 5; ++ct)
          #pragma unroll
          for (int r = 0; r < 4; ++r) {
            int i = w * 16 + hi * 4 + r, j = ct * 16 + lo;
            if (i < NTU && j < NTU && i != j)
              cs += fabsf(acc[ct][r]) * invs[i] * invs[j];
          }
      }
      #pragma unroll
      for (int m = 1; m < 64; m <<= 1) cs += __shfl_xor(cs, m, 64);
      if (lane == 0 && w < 5) rbuf5[w] = cs;
      __syncthreads();
      if (tid == 0) {
        float s = 0.f;
        for (int i = 0; i < 5; ++i) s += rbuf5[i];
        part[256 + b] = s;
      }
      __syncthreads();   // rbuf5/invs free before next half
    }
  } else {
    // ================= global projection (1 row per block; tid<256 active) =========
    float* srow = (float*)&As[0][0];
    float* rb = &redS[0][0];
    const int row = bid - 692;            // 0..511
    const bool isv = row < 256;
    const int r2 = row & 255;
    const int K = isv ? 768 : 512;
    const float* src = isv ? vsrc : tsrc;
    const short* WT = isv ? gvWT : gtWT;
    const float* bias = isv ? gvb : gtb;
    const float* gg = isv ? gvg : gtg;
    const float* bt = isv ? gvbt : gtbt;
    float* outp = isv ? outVG : outTG;
    const bool act = tid < 256;

    for (int k = tid; k < K; k += 1024) srow[k] = src[(size_t)r2 * K + k];
    __syncthreads();
    float v0 = 0.f, v1 = 0.f;
    if (act) {
      const short* wp0 = WT + (size_t)tid * K;
      const short* wp1 = WT + (size_t)(tid + 256) * K;
      for (int k = 0; k < K; k += 8) {
        short8 wa = *(const short8*)(wp0 + k);
        short8 wb = *(const short8*)(wp1 + k);
        #pragma unroll
        for (int j = 0; j < 8; ++j) {
          float sv = srow[k + j];
          v0 += sv * bf2f(wa[j]);
          v1 += sv * bf2f(wb[j]);
        }
      }
      v0 += bias[tid]; v1 += bias[tid + 256];
    }
    float s = act ? (v0 + v1) : 0.f;
    float q = act ? (v0 * v0 + v1 * v1) : 0.f;
    #pragma unroll
    for (int m = 1; m < 64; m <<= 1) {
      s += __shfl_xor(s, m, 64);
      q += __shfl_xor(q, m, 64);
    }
    if (lane == 0 && w < 4) { rb[w] = s; rb[4 + w] = q; }
    __syncthreads();
    s = rb[0] + rb[1] + rb[2] + rb[3];
    q = rb[4] + rb[5] + rb[6] + rb[7];
    __syncthreads();
    float mu = s * (1.f / 512.f);
    float var = q * (1.f / 512.f) - mu * mu;
    float rs = rsqrtf(var + 1e-5f);
    float y0 = 0.f, y1 = 0.f;
    if (act) {
      y0 = (v0 - mu) * rs * gg[tid] + bt[tid];
      y1 = (v1 - mu) * rs * gg[tid + 256] + bt[tid + 256];
    }
    float ss = act ? (y0 * y0 + y1 * y1) : 0.f;
    #pragma unroll
    for (int m = 1; m < 64; m <<= 1) ss += __shfl_xor(ss, m, 64);
    if (lane == 0 && w < 4) rb[w] = ss;
    __syncthreads();
    ss = rb[0] + rb[1] + rb[2] + rb[3];
    float invn = 1.f / fmaxf(sqrtf(ss), 1e-12f);
    if (act) {
      float o0 = y0 * invn, o1 = y1 * invn;
      outp[(size_t)r2 * 512 + tid] = o0;
      outp[(size_t)r2 * 512 + tid + 256] = o1;
      if (!isv) {
        Tt[(size_t)tid * 256 + r2] = o0;
        Tt[(size_t)(tid + 256) * 256 + r2] = o1;
      }
    }
  }
}

// ---------------- logits rows: coalesced via T^T; writes logits + logits^T ----------------
__global__ __launch_bounds__(256) void k_logits_row(
    const float* __restrict__ vgp, const float* __restrict__ Tt,
    const float* __restrict__ lsc, float* __restrict__ logits,
    float* __restrict__ logitsT,
    float* __restrict__ diag, float* __restrict__ rlse) {
  __shared__ __align__(16) float vrow[512];
  __shared__ float rbuf[4];
  const int i = blockIdx.x, tid = threadIdx.x;
  const float scale = fminf(expf(lsc[0]), 100.f);
  vrow[tid] = vgp[(size_t)i * 512 + tid];
  vrow[tid + 256] = vgp[(size_t)i * 512 + 256 + tid];
  __syncthreads();
  float s = 0.f;
  #pragma unroll 8
  for (int k = 0; k < 512; ++k)
    s += vrow[k] * Tt[(size_t)k * 256 + tid];
  float lg = scale * s;
  logits[(size_t)i * 256 + tid] = lg;
  logitsT[(size_t)tid * 256 + i] = lg;
  if (tid == i) diag[i] = lg;
  float mx = blk_max_(lg, rbuf, 4);
  float se = blk_sum_(expf(lg - mx), rbuf, 4);
  if (tid == 0) rlse[i] = mx + logf(se);
}

// ---------------- logits cols: coalesced via logits^T ----------------
__global__ __launch_bounds__(256) void k_logits_col(
    const float* __restrict__ logitsT, float* __restrict__ clse) {
  __shared__ float rbuf[4];
  const int j = blockIdx.x, tid = threadIdx.x;
  float lg = logitsT[(size_t)j * 256 + tid];
  float mx = blk_max_(lg, rbuf, 4);
  float se = blk_sum_(expf(lg - mx), rbuf, 4);
  if (tid == 0) clse[j] = mx + logf(se);
}

// ---------------- per-batch sim + mutual-NN unit loss (512 thr, K-split) ----------------
__global__ __launch_bounds__(512) void k_unit_sim(
    const float* __restrict__ vpp, const float* __restrict__ tpp,
    const float* __restrict__ lsc, float* __restrict__ simout,
    float* __restrict__ up, float* __restrict__ uc) {
  __shared__ float Sp[2][64][81];
  __shared__ float lse_r[64];
  __shared__ int bestt[64];
  __shared__ float lse_c[80];
  __shared__ int bestv[80];
  __shared__ float rbuf[8];
  const int b = blockIdx.x;
  const int tid = threadIdx.x;
  const int w = tid >> 6, lane = tid & 63;
  const int wq = w >> 1, kg = w & 1;
  const int hi = lane >> 4, lo = lane & 15;
  const float scale = fminf(expf(lsc[0]), 100.f);

  f32x4 acc[5];
  #pragma unroll
  for (int ct = 0; ct < 5; ++ct) acc[ct] = (f32x4){0.f, 0.f, 0.f, 0.f};

  const float* va = vpp + ((size_t)b * 64 + wq * 16 + lo) * 512 + kg * 256;
  const float* tbase = tpp + (size_t)b * 77 * 512 + kg * 256;
  for (int k0 = 0; k0 < 256; k0 += 32) {
    float4 f0 = *(const float4*)(va + k0 + hi * 8);
    float4 f1 = *(const float4*)(va + k0 + hi * 8 + 4);
    short8 a = {f2bf(f0.x), f2bf(f0.y), f2bf(f0.z), f2bf(f0.w),
                f2bf(f1.x), f2bf(f1.y), f2bf(f1.z), f2bf(f1.w)};
    #pragma unroll
    for (int ct = 0; ct < 5; ++ct) {
      int rj = ct * 16 + lo;
      short8 bb = {0, 0, 0, 0, 0, 0, 0, 0};
      if (rj < 77) {
        const float* tb = tbase + (size_t)rj * 512 + k0 + hi * 8;
        float4 g0 = *(const float4*)tb;
        float4 g1 = *(const float4*)(tb + 4);
        bb = (short8){f2bf(g0.x), f2bf(g0.y), f2bf(g0.z), f2bf(g0.w),
                      f2bf(g1.x), f2bf(g1.y), f2bf(g1.z), f2bf(g1.w)};
      }
      acc[ct] = __builtin_amdgcn_mfma_f32_16x16x32_bf16(a, bb, acc[ct], 0, 0, 0);
    }
  }
  #pragma unroll
  for (int ct = 0; ct < 5; ++ct)
    #pragma unroll
    for (int r = 0; r < 4; ++r) {
      int i = wq * 16 + hi * 4 + r, j = ct * 16 + lo;
      if (j < 77) Sp[kg][i][j] = acc[ct][r];
    }
  __syncthreads();
  for (int idx = tid; idx < 64 * 77; idx += 512) {
    int i = idx / 77, j = idx - i * 77;
    float s = Sp[0][i][j] + Sp[1][i][j];
    simout[((size_t)b * 64 + i) * 77 + j] = s;
    Sp[0][i][j] = s * scale;
  }
  __syncthreads();
  if (tid < 64) {
    float mx = -1e30f; int am = 0;
    for (int t = 0; t < 77; ++t) { float x = Sp[0][tid][t]; if (x > mx) { mx = x; am = t; } }
    float se = 0.f;
    for (int t = 0; t < 77; ++t) se += expf(Sp[0][tid][t] - mx);
    lse_r[tid] = mx + logf(se); bestt[tid] = am;
  } else if (tid < 64 + 77) {
    int t = tid - 64;
    float mx = -1e30f; int am = 0;
    for (int v = 0; v < 64; ++v) { float x = Sp[0][v][t]; if (x > mx) { mx = x; am = v; } }
    float se = 0.f;
    for (int v = 0; v < 64; ++v) se += expf(Sp[0][v][t] - mx);
    lse_c[t] = mx + logf(se); bestv[t] = am;
  }
  __syncthreads();
  float c = 0.f, cnt = 0.f;
  if (tid < 64) {
    int j = bestt[tid];
    if (bestv[j] == tid) {
      float sv = Sp[0][tid][j];
      c = -((sv - lse_r[tid]) + (sv - lse_c[j]));
      cnt = 2.f;
    }
  }
  c = blk_sum_(c, rbuf, 8);
  cnt = blk_sum_(cnt, rbuf, 8);
  if (tid == 0) { up[b] = c; uc[b] = cnt; }
}

// ---------------- final scalar losses ----------------
__global__ __launch_bounds__(256) void k_final(
    const float* __restrict__ diag, const float* __restrict__ rlse,
    const float* __restrict__ clse, const float* __restrict__ up,
    const float* __restrict__ uc, const float* __restrict__ part,
    float* __restrict__ out) {
  __shared__ float rbuf[4];
  const int tid = threadIdx.x;
  float d = diag[tid];
  float s1 = blk_sum_(d - rlse[tid], rbuf, 4);
  float s2 = blk_sum_(d - clse[tid], rbuf, 4);
  float su = blk_sum_(up[tid], rbuf, 4);
  float sc = blk_sum_(uc[tid], rbuf, 4);
  float sv = blk_sum_(part[tid], rbuf, 4);
  float st = blk_sum_(part[tid + 256], rbuf, 4);
  if (tid == 0) {
    out[0] = -(s1 * (1.f / 256.f) + s2 * (1.f / 256.f)) * 0.5f;
    out[1] = su / fmaxf(sc, 1.f);
    out[2] = (sv / (256.f * 64.f * 63.f) + st / (256.f * 77.f * 76.f)) * 0.5f;
  }
}

extern "C" void kernel_launch(void* const* d_in, const int* in_sizes, int n_in,
                              void* d_out, int out_size, void* d_ws, size_t ws_size,
                              hipStream_t stream) {
  const float* vis_units = (const float*)d_in[0];
  const float* txt_units = (const float*)d_in[1];
  const float* vis_cls = (const float*)d_in[2];
  const float* txt_cls = (const float*)d_in[3];
  const float* vW1 = (const float*)d_in[4];
  const float* vb1 = (const float*)d_in[5];
  const float* vg  = (const float*)d_in[6];
  const float* vbt = (const float*)d_in[7];
  const float* vW2 = (const float*)d_in[8];
  const float* vb2 = (const float*)d_in[9];
  const float* tW1 = (const float*)d_in[10];
  const float* tb1 = (const float*)d_in[11];
  const float* tg  = (const float*)d_in[12];
  const float* tbt = (const float*)d_in[13];
  const float* tW2 = (const float*)d_in[14];
  const float* tb2 = (const float*)d_in[15];
  const float* gvW = (const float*)d_in[16];
  const float* gvb = (const float*)d_in[17];
  const float* gvg = (const float*)d_in[18];
  const float* gvbt = (const float*)d_in[19];
  const float* gtW = (const float*)d_in[20];
  const float* gtb = (const float*)d_in[21];
  const float* gtg = (const float*)d_in[22];
  const float* gtbt = (const float*)d_in[23];
  const float* lsc = (const float*)d_in[24];

  float* out = (float*)d_out;
  char* ws = (char*)d_ws;
  short* vW1T = (short*)(ws + WS_VW1T);
  short* vW2T = (short*)(ws + WS_VW2T);
  short* tW1T = (short*)(ws + WS_TW1T);
  short* tW2T = (short*)(ws + WS_TW2T);
  short* gvWT = (short*)(ws + WS_GVWT);
  short* gtWT = (short*)(ws + WS_GTWT);
  float* logits = (float*)(ws + WS_LOG);
  float* diag = (float*)(ws + WS_DIAG);
  float* rlse = (float*)(ws + WS_RLSE);
  float* clse = (float*)(ws + WS_CLSE);
  float* up = (float*)(ws + WS_UP);
  float* uc = (float*)(ws + WS_UC);
  float* part = (float*)(ws + WS_PART);
  float* Tt = (float*)(ws + WS_TT);
  float* logitsT = (float*)(ws + WS_LOGT);

  // merged prep (weight fragment cvt + global-proj transposes)
  k_prep<<<3072, 256, 0, stream>>>(vW1, vW2, tW1, tW2, vW1T, vW2T, tW1T, tW2T,
                                   gvW, gvWT, gtW, gtWT);

  // mega: unit MLPs (+fused vis diversity) + txt diversity + global projections
  k_mega<<<1204, 1024, 0, stream>>>(
      vis_units, txt_units,
      vW1T, vb1, vg, vbt, vW2T, vb2,
      tW1T, tb1, tg, tbt, tW2T, tb2,
      out + O_VP, out + O_TP,
      vis_cls, txt_cls,
      gvWT, gvb, gvg, gvbt, gtWT, gtb, gtg, gtbt,
      out + O_VG, out + O_TG, Tt, part);

  // global CLIP loss pieces
  k_logits_row<<<256, 256, 0, stream>>>(out + O_VG, Tt, lsc, logits, logitsT, diag, rlse);
  k_logits_col<<<256, 256, 0, stream>>>(logitsT, clse);

  // unit sim + mutual-NN loss partials (+ sim_matrix output)
  k_unit_sim<<<256, 512, 0, stream>>>(out + O_VP, out + O_TP, lsc, out + O_SM, up, uc);

  // final scalars
  k_final<<<1, 256, 0, stream>>>(diag, rlse, clse, up, uc, part, out);

  (void)in_sizes; (void)n_in; (void)out_size; (void)ws_size;
}

// Round 22
// 229.464 us; speedup vs baseline: 1.0068x; 1.0068x over previous
//
#include <hip/hip_runtime.h>
#include <math.h>

typedef __attribute__((ext_vector_type(8))) short short8;
typedef __attribute__((ext_vector_type(4))) short short4v;
typedef __attribute__((ext_vector_type(4))) float f32x4;

#define NB 256
#define NVU 64
#define NTU 77
#define PD 512

// ---- d_out offsets (in floats) ----
#define O_VP 3ull
#define O_TP (O_VP + (size_t)NB * NVU * PD)
#define O_VG (O_TP + (size_t)NB * NTU * PD)
#define O_TG (O_VG + (size_t)NB * PD)
#define O_SM (O_TG + (size_t)NB * PD)

// ---- ws offsets (bytes) ----
#define WS_VW1T 0u
#define WS_VW2T 524288u
#define WS_TW1T 1048576u
#define WS_TW2T 1572864u
#define WS_GVWT 2097152u
#define WS_GTWT 2883584u
#define WS_LOG  3552256u
#define WS_DIAG 3814400u
#define WS_RLSE 3815424u
#define WS_CLSE 3816448u
#define WS_UP   3817472u
#define WS_UC   3818496u
#define WS_PART 3819520u   // 512 floats -> ends 3821568
#define WS_TT   3821568u   // t_global^T f32[512][256] = 524288
#define WS_LOGT 4345856u   // logits^T f32[256][256] = 262144

// async global->LDS, 16B per lane; LDS dest = wave-uniform base + lane*16
#define GL_LDS16(gp, lp) __builtin_amdgcn_global_load_lds( \
    (const __attribute__((address_space(1))) void*)(gp), \
    (__attribute__((address_space(3))) void*)(lp), 16, 0, 0)

__device__ inline short f2bf(float f) {
  union { float f; unsigned u; } v; v.f = f;
  unsigned r = v.u + 0x7FFFu + ((v.u >> 16) & 1u);   // RNE
  return (short)(r >> 16);
}
__device__ inline float bf2f(short s) {
  union { unsigned u; float f; } v; v.u = ((unsigned)(unsigned short)s) << 16;
  return v.f;
}

__device__ inline float blk_sum_(float x, float* buf, int nw) {
  const int lane = threadIdx.x & 63, w = threadIdx.x >> 6;
  #pragma unroll
  for (int m = 1; m < 64; m <<= 1) x += __shfl_xor(x, m, 64);
  __syncthreads();
  if (lane == 0) buf[w] = x;
  __syncthreads();
  float s = 0.f;
  for (int i = 0; i < nw; ++i) s += buf[i];
  return s;
}
__device__ inline float blk_max_(float x, float* buf, int nw) {
  const int lane = threadIdx.x & 63, w = threadIdx.x >> 6;
  #pragma unroll
  for (int m = 1; m < 64; m <<= 1) x = fmaxf(x, __shfl_xor(x, m, 64));
  __syncthreads();
  if (lane == 0) buf[w] = x;
  __syncthreads();
  float s = buf[0];
  for (int i = 1; i < nw; ++i) s = fmaxf(s, buf[i]);
  return s;
}

// ---------------- merged prep: unit-weight fragment cvt (bids 0..511) +
//                  global-proj transposes (bids 512..3071) ----------------
__global__ __launch_bounds__(256) void k_prep(
    const float* __restrict__ s0, const float* __restrict__ s1,
    const float* __restrict__ s2, const float* __restrict__ s3,
    short* __restrict__ d0, short* __restrict__ d1,
    short* __restrict__ d2, short* __restrict__ d3,
    const float* __restrict__ gv, short* __restrict__ dv_,
    const float* __restrict__ gt, short* __restrict__ dt_) {
  __shared__ short tile[32][66];
  const int bid = blockIdx.x;
  if (bid < 512) {
    const int m = bid >> 7;
    const float* src = m == 0 ? s0 : m == 1 ? s1 : m == 2 ? s2 : s3;
    short* dst = m == 0 ? d0 : m == 1 ? d1 : m == 2 ? d2 : d3;
    const int rem = bid & 127;
    const int kc = rem >> 3, nt = rem & 7;
    const int n0 = nt * 64;
    #pragma unroll
    for (int it = 0; it < 8; ++it) {
      int idx = it * 256 + threadIdx.x;
      int r = idx >> 6, c = idx & 63;
      tile[r][c] = f2bf(src[(size_t)(kc * 32 + r) * 512 + n0 + c]);
    }
    __syncthreads();
    const int nl = threadIdx.x >> 2, s = threadIdx.x & 3;
    const int n = n0 + nl;
    short8 v;
    #pragma unroll
    for (int j = 0; j < 8; ++j) v[j] = tile[s * 8 + j][nl];
    *(short8*)&dst[(size_t)kc * 16384 + n * 32 + ((s ^ ((n >> 1) & 3)) << 3)] = v;
  } else if (bid < 2048) {
    int idx = (bid - 512) * 256 + threadIdx.x;      // 768*512
    int k = idx >> 9, n = idx & 511;
    dv_[(size_t)n * 768 + k] = f2bf(gv[idx]);
  } else {
    int idx = (bid - 2048) * 256 + threadIdx.x;     // 512*512
    int k = idx >> 9, n = idx & 511;
    dt_[(size_t)n * 512 + k] = f2bf(gt[idx]);
  }
}

// ---------------- mega kernel: mlp+vis-div (0..563) + txt-div (564..691) + gproj (692..1203) ----
__global__ __launch_bounds__(1024) void k_mega(
    const float* __restrict__ Xv, const float* __restrict__ Xt,
    const short* __restrict__ vWf1, const float* __restrict__ vb1,
    const float* __restrict__ vg, const float* __restrict__ vbt,
    const short* __restrict__ vWf2, const float* __restrict__ vb2,
    const short* __restrict__ tWf1, const float* __restrict__ tb1,
    const float* __restrict__ tg, const float* __restrict__ tbt,
    const short* __restrict__ tWf2, const float* __restrict__ tb2,
    float* __restrict__ outV, float* __restrict__ outT,
    const float* __restrict__ vsrc, const float* __restrict__ tsrc,
    const short* __restrict__ gvWT, const float* __restrict__ gvb,
    const float* __restrict__ gvg, const float* __restrict__ gvbt,
    const short* __restrict__ gtWT, const float* __restrict__ gtb,
    const float* __restrict__ gtg, const float* __restrict__ gtbt,
    float* __restrict__ outVG, float* __restrict__ outTG,
    float* __restrict__ Tt, float* __restrict__ part) {
  __shared__ __align__(16) short As[64][520];      // 66560 B
  __shared__ __align__(16) short Bs[2][16384];     // 65536 B
  __shared__ float redS[4][64];
  __shared__ float redQ[4][64];

  const int tid = threadIdx.x;
  const int w = tid >> 6, lane = tid & 63;
  const int hi = lane >> 4, lo = lane & 15;
  const int bid = blockIdx.x;

  if (bid < 564) {
    // ================= unit MLP (r15 structure) + fused vis diversity =================
    const int rg = w >> 2, cg = w & 3;
    // bijective XCD swizzle for 564 = 8*70 + 4 (m204)
    const int xcd = bid & 7, ii = bid >> 3;
    const int orig = (xcd < 4 ? xcd * 71 : 284 + (xcd - 4) * 70) + ii;
    const bool isv = orig < 256;
    const int rb = isv ? orig : orig - 256;
    const float* __restrict__ X   = isv ? Xv : Xt;
    const short* __restrict__ Wf1 = isv ? vWf1 : tWf1;
    const float* __restrict__ b1  = isv ? vb1  : tb1;
    const float* __restrict__ gg  = isv ? vg   : tg;
    const float* __restrict__ bt  = isv ? vbt  : tbt;
    const short* __restrict__ Wf2 = isv ? vWf2 : tWf2;
    const float* __restrict__ b2  = isv ? vb2  : tb2;
    float* __restrict__ outF      = isv ? outV : outT;
    const size_t row0 = (size_t)rb * 64;

    const int arow = rg * 16 + lo;
    const int bswz = (cg * 128 + lo) * 32 + ((hi ^ ((lo >> 1) & 3)) * 8);

    GL_LDS16(Wf1 + tid * 8, &Bs[0][tid * 8]);
    GL_LDS16(Wf1 + 8192 + tid * 8, &Bs[0][8192 + tid * 8]);

    const f32x4* Xp = (const f32x4*)(X + row0 * 512);
    #pragma unroll
    for (int i = 0; i < 8; ++i) {
      int idx = i * 1024 + tid;
      f32x4 f = __builtin_nontemporal_load(Xp + idx);
      short4v s4 = {f2bf(f[0]), f2bf(f[1]), f2bf(f[2]), f2bf(f[3])};
      *(short4v*)&As[idx >> 7][(idx & 127) * 4] = s4;
    }
    __syncthreads();   // X + W1 chunk 0 resident

    // issue W1 chunk 1 (2 in flight)
    GL_LDS16(Wf1 + 16384 + tid * 8, &Bs[1][tid * 8]);
    GL_LDS16(Wf1 + 16384 + 8192 + tid * 8, &Bs[1][8192 + tid * 8]);

    if (isv) {
      // ---- fused vis-diversity gram on raw X tile (batch rb == 64 rows) ----
      // wave w computes 16x16 gram tile (ti, tj); C layout: row=hi*4+r, col=lo (m89)
      const int ti = rg, tj = cg;
      f32x4 g = (f32x4){0.f, 0.f, 0.f, 0.f};
      for (int kc = 0; kc < 16; ++kc) {
        short8 ga = *(const short8*)&As[ti * 16 + lo][kc * 32 + hi * 8];
        short8 gb = *(const short8*)&As[tj * 16 + lo][kc * 32 + hi * 8];
        g = __builtin_amdgcn_mfma_f32_16x16x32_bf16(ga, gb, g, 0, 0, 0);
      }
      float* invs = &redQ[0][0];          // 64 floats (redQ free until GEMM1 epilogue)
      if (ti == tj && (lo >> 2) == hi)
        invs[ti * 16 + lo] = 1.f / fmaxf(sqrtf(fmaxf(g[lo & 3], 0.f)), 1e-12f);
      __syncthreads();
      float cs = 0.f;
      #pragma unroll
      for (int r = 0; r < 4; ++r) {
        int i = ti * 16 + hi * 4 + r, j = tj * 16 + lo;
        if (i != j) cs += fabsf(g[r]) * invs[i] * invs[j];
      }
      #pragma unroll
      for (int m = 1; m < 64; m <<= 1) cs += __shfl_xor(cs, m, 64);
      if (lane == 0) redS[0][w] = cs;
      __syncthreads();
      if (tid == 0) {
        float s = 0.f;
        #pragma unroll
        for (int i = 0; i < 16; ++i) s += redS[0][i];
        part[rb] = s;
      }
    }

    f32x4 acc[8];
    #pragma unroll
    for (int ct = 0; ct < 8; ++ct) acc[ct] = (f32x4){0.f, 0.f, 0.f, 0.f};

    for (int kc = 0; kc < 16; ++kc) {
      const int cur = kc & 1;
      short8 a = *(const short8*)&As[arow][kc * 32 + hi * 8];
      #pragma unroll
      for (int ct = 0; ct < 8; ++ct) {
        short8 bb = *(const short8*)&Bs[cur][bswz + ct * 512];
        acc[ct] = __builtin_amdgcn_mfma_f32_16x16x32_bf16(a, bb, acc[ct], 0, 0, 0);
      }
      __builtin_amdgcn_s_barrier();
      const int nc = kc + 2;
      const short* nxt = (nc < 16) ? (Wf1 + (size_t)nc * 16384)
                                   : (Wf2 + (size_t)(nc - 16) * 16384);
      GL_LDS16(nxt + tid * 8, &Bs[cur][tid * 8]);
      GL_LDS16(nxt + 8192 + tid * 8, &Bs[cur][8192 + tid * 8]);
      asm volatile("s_waitcnt vmcnt(2)" ::: "memory");
    }

    {
      float ps[4] = {0.f, 0.f, 0.f, 0.f}, pq[4] = {0.f, 0.f, 0.f, 0.f};
      #pragma unroll
      for (int ct = 0; ct < 8; ++ct) {
        float bia = b1[cg * 128 + ct * 16 + lo];
        #pragma unroll
        for (int r = 0; r < 4; ++r) {
          float v = acc[ct][r] + bia;
          acc[ct][r] = v;
          ps[r] += v; pq[r] += v * v;
        }
      }
      #pragma unroll
      for (int m = 1; m < 16; m <<= 1)
        #pragma unroll
        for (int r = 0; r < 4; ++r) {
          ps[r] += __shfl_xor(ps[r], m, 64);
          pq[r] += __shfl_xor(pq[r], m, 64);
        }
      if (lo == 0) {
        #pragma unroll
        for (int r = 0; r < 4; ++r) {
          int rr = rg * 16 + hi * 4 + r;
          redS[cg][rr] = ps[r]; redQ[cg][rr] = pq[r];
        }
      }
    }
    __syncthreads();

    {
      float mu[4], rs[4];
      #pragma unroll
      for (int r = 0; r < 4; ++r) {
        int rr = rg * 16 + hi * 4 + r;
        float s = redS[0][rr] + redS[1][rr] + redS[2][rr] + redS[3][rr];
        float q = redQ[0][rr] + redQ[1][rr] + redQ[2][rr] + redQ[3][rr];
        float m_ = s * (1.f / 512.f);
        mu[r] = m_;
        rs[r] = rsqrtf(q * (1.f / 512.f) - m_ * m_ + 1e-5f);
      }
      #pragma unroll
      for (int ct = 0; ct < 8; ++ct) {
        int col = cg * 128 + ct * 16 + lo;
        float ga = gg[col], be = bt[col];
        #pragma unroll
        for (int r = 0; r < 4; ++r) {
          float xn = (acc[ct][r] - mu[r]) * rs[r] * ga + be;
          float ge = 0.5f * xn * (1.f + erff(xn * 0.70710678118654752f));
          As[rg * 16 + hi * 4 + r][col] = f2bf(ge);
        }
      }
    }
    __syncthreads();

    #pragma unroll
    for (int ct = 0; ct < 8; ++ct) acc[ct] = (f32x4){0.f, 0.f, 0.f, 0.f};
    for (int kc = 0; kc < 16; ++kc) {
      const int cur = kc & 1;
      short8 a = *(const short8*)&As[arow][kc * 32 + hi * 8];
      #pragma unroll
      for (int ct = 0; ct < 8; ++ct) {
        short8 bb = *(const short8*)&Bs[cur][bswz + ct * 512];
        acc[ct] = __builtin_amdgcn_mfma_f32_16x16x32_bf16(a, bb, acc[ct], 0, 0, 0);
      }
      __builtin_amdgcn_s_barrier();
      if (kc < 14) {
        const short* nxt = Wf2 + (size_t)(kc + 2) * 16384;
        GL_LDS16(nxt + tid * 8, &Bs[cur][tid * 8]);
        GL_LDS16(nxt + 8192 + tid * 8, &Bs[cur][8192 + tid * 8]);
        asm volatile("s_waitcnt vmcnt(2)" ::: "memory");
      } else if (kc == 14) {
        asm volatile("s_waitcnt vmcnt(0)" ::: "memory");
      }
    }

    {
      float pq[4] = {0.f, 0.f, 0.f, 0.f};
      #pragma unroll
      for (int ct = 0; ct < 8; ++ct) {
        float bia = b2[cg * 128 + ct * 16 + lo];
        #pragma unroll
        for (int r = 0; r < 4; ++r) {
          float v = acc[ct][r] + bia;
          acc[ct][r] = v;
          pq[r] += v * v;
        }
      }
      #pragma unroll
      for (int m = 1; m < 16; m <<= 1)
        #pragma unroll
        for (int r = 0; r < 4; ++r) pq[r] += __shfl_xor(pq[r], m, 64);
      if (lo == 0) {
        #pragma unroll
        for (int r = 0; r < 4; ++r) redQ[cg][rg * 16 + hi * 4 + r] = pq[r];
      }
    }
    __syncthreads();
    {
      float invn[4];
      #pragma unroll
      for (int r = 0; r < 4; ++r) {
        int rr = rg * 16 + hi * 4 + r;
        float q = redQ[0][rr] + redQ[1][rr] + redQ[2][rr] + redQ[3][rr];
        invn[r] = 1.f / fmaxf(sqrtf(q), 1e-12f);
      }
      #pragma unroll
      for (int ct = 0; ct < 8; ++ct) {
        int col = cg * 128 + ct * 16 + lo;
        #pragma unroll
        for (int r = 0; r < 4; ++r)
          outF[(row0 + rg * 16 + hi * 4 + r) * 512 + col] = acc[ct][r] * invn[r];
      }
    }
  } else if (bid < 692) {
    // ================= txt diversity (2 batches per block; tid<320 for MFMA) ========
    short (*Bsd)[136] = (short(*)[136])&As[0][0];   // 80*136*2 = 21760 B
    float* invs = &redQ[0][0];                       // 80 floats
    float* rbuf5 = &redS[0][0];                      // 5 floats
    const int ri = w * 16 + lo;
    for (int half = 0; half < 2; ++half) {
      const int b = (bid - 564) * 2 + half;          // 0..255
      const float* X = Xt + (size_t)b * NTU * 512;
      f32x4 acc[5];
      #pragma unroll
      for (int ct = 0; ct < 5; ++ct) acc[ct] = (f32x4){0.f, 0.f, 0.f, 0.f};

      for (int c = 0; c < 4; ++c) {
        for (int s5 = tid; s5 < 80 * 32; s5 += 1024) {
          int r = s5 >> 5, cgp = s5 & 31;
          short4v s4 = {0, 0, 0, 0};
          if (r < NTU) {
            float4 f = *(const float4*)(X + (size_t)r * 512 + c * 128 + cgp * 4);
            s4 = (short4v){f2bf(f.x), f2bf(f.y), f2bf(f.z), f2bf(f.w)};
          }
          *(short4v*)&Bsd[r][cgp * 4] = s4;
        }
        __syncthreads();
        if (tid < 320) {
          #pragma unroll
          for (int kc = 0; kc < 4; ++kc) {
            short8 a = *(const short8*)&Bsd[ri][kc * 32 + hi * 8];
            #pragma unroll
            for (int ct = 0; ct < 5; ++ct) {
              short8 bb = *(const short8*)&Bsd[ct * 16 + lo][kc * 32 + hi * 8];
              acc[ct] = __builtin_amdgcn_mfma_f32_16x16x32_bf16(a, bb, acc[ct], 0, 0, 0);
            }
          }
        }
        __syncthreads();
      }

      if (tid < 320) {
        #pragma unroll
        for (int ct = 0; ct < 5; ++ct)
          #pragma unroll
          for (int r = 0; r < 4; ++r) {
            int i = w * 16 + hi * 4 + r, j = ct * 16 + lo;
            if (i == j && i < NTU) invs[i] = 1.f / fmaxf(sqrtf(fmaxf(acc[ct][r], 0.f)), 1e-12f);
          }
      }
      __syncthreads();

      float cs = 0.f;
      if (tid < 320) {
        #pragma unroll
        for (int ct = 0; ct < 5; ++ct)
          #pragma unroll
          for (int r = 0; r < 4; ++r) {
            int i = w * 16 + hi * 4 + r, j = ct * 16 + lo;
            if (i < NTU && j < NTU && i != j)
              cs += fabsf(acc[ct][r]) * invs[i] * invs[j];
          }
      }
      #pragma unroll
      for (int m = 1; m < 64; m <<= 1) cs += __shfl_xor(cs, m, 64);
      if (lane == 0 && w < 5) rbuf5[w] = cs;
      __syncthreads();
      if (tid == 0) {
        float s = 0.f;
        for (int i = 0; i < 5; ++i) s += rbuf5[i];
        part[256 + b] = s;
      }
      __syncthreads();   // rbuf5/invs free before next half
    }
  } else {
    // ================= global projection (1 row per block; tid<256 active) =========
    float* srow = (float*)&As[0][0];
    float* rb = &redS[0][0];
    const int row = bid - 692;            // 0..511
    const bool isv = row < 256;
    const int r2 = row & 255;
    const int K = isv ? 768 : 512;
    const float* src = isv ? vsrc : tsrc;
    const short* WT = isv ? gvWT : gtWT;
    const float* bias = isv ? gvb : gtb;
    const float* gg = isv ? gvg : gtg;
    const float* bt = isv ? gvbt : gtbt;
    float* outp = isv ? outVG : outTG;
    const bool act = tid < 256;

    for (int k = tid; k < K; k += 1024) srow[k] = src[(size_t)r2 * K + k];
    __syncthreads();
    float v0 = 0.f, v1 = 0.f;
    if (act) {
      const short* wp0 = WT + (size_t)tid * K;
      const short* wp1 = WT + (size_t)(tid + 256) * K;
      for (int k = 0; k < K; k += 8) {
        short8 wa = *(const short8*)(wp0 + k);
        short8 wb = *(const short8*)(wp1 + k);
        #pragma unroll
        for (int j = 0; j < 8; ++j) {
          float sv = srow[k + j];
          v0 += sv * bf2f(wa[j]);
          v1 += sv * bf2f(wb[j]);
        }
      }
      v0 += bias[tid]; v1 += bias[tid + 256];
    }
    float s = act ? (v0 + v1) : 0.f;
    float q = act ? (v0 * v0 + v1 * v1) : 0.f;
    #pragma unroll
    for (int m = 1; m < 64; m <<= 1) {
      s += __shfl_xor(s, m, 64);
      q += __shfl_xor(q, m, 64);
    }
    if (lane == 0 && w < 4) { rb[w] = s; rb[4 + w] = q; }
    __syncthreads();
    s = rb[0] + rb[1] + rb[2] + rb[3];
    q = rb[4] + rb[5] + rb[6] + rb[7];
    __syncthreads();
    float mu = s * (1.f / 512.f);
    float var = q * (1.f / 512.f) - mu * mu;
    float rs = rsqrtf(var + 1e-5f);
    float y0 = 0.f, y1 = 0.f;
    if (act) {
      y0 = (v0 - mu) * rs * gg[tid] + bt[tid];
      y1 = (v1 - mu) * rs * gg[tid + 256] + bt[tid + 256];
    }
    float ss = act ? (y0 * y0 + y1 * y1) : 0.f;
    #pragma unroll
    for (int m = 1; m < 64; m <<= 1) ss += __shfl_xor(ss, m, 64);
    if (lane == 0 && w < 4) rb[w] = ss;
    __syncthreads();
    ss = rb[0] + rb[1] + rb[2] + rb[3];
    float invn = 1.f / fmaxf(sqrtf(ss), 1e-12f);
    if (act) {
      float o0 = y0 * invn, o1 = y1 * invn;
      outp[(size_t)r2 * 512 + tid] = o0;
      outp[(size_t)r2 * 512 + tid + 256] = o1;
      if (!isv) {
        Tt[(size_t)tid * 256 + r2] = o0;
        Tt[(size_t)(tid + 256) * 256 + r2] = o1;
      }
    }
  }
}

// ---------------- logits rows: coalesced via T^T; writes logits + logits^T ----------------
__global__ __launch_bounds__(256) void k_logits_row(
    const float* __restrict__ vgp, const float* __restrict__ Tt,
    const float* __restrict__ lsc, float* __restrict__ logits,
    float* __restrict__ logitsT,
    float* __restrict__ diag, float* __restrict__ rlse) {
  __shared__ __align__(16) float vrow[512];
  __shared__ float rbuf[4];
  const int i = blockIdx.x, tid = threadIdx.x;
  const float scale = fminf(expf(lsc[0]), 100.f);
  vrow[tid] = vgp[(size_t)i * 512 + tid];
  vrow[tid + 256] = vgp[(size_t)i * 512 + 256 + tid];
  __syncthreads();
  float s = 0.f;
  #pragma unroll 8
  for (int k = 0; k < 512; ++k)
    s += vrow[k] * Tt[(size_t)k * 256 + tid];
  float lg = scale * s;
  logits[(size_t)i * 256 + tid] = lg;
  logitsT[(size_t)tid * 256 + i] = lg;
  if (tid == i) diag[i] = lg;
  float mx = blk_max_(lg, rbuf, 4);
  float se = blk_sum_(expf(lg - mx), rbuf, 4);
  if (tid == 0) rlse[i] = mx + logf(se);
}

// ---------------- logits cols: coalesced via logits^T ----------------
__global__ __launch_bounds__(256) void k_logits_col(
    const float* __restrict__ logitsT, float* __restrict__ clse) {
  __shared__ float rbuf[4];
  const int j = blockIdx.x, tid = threadIdx.x;
  float lg = logitsT[(size_t)j * 256 + tid];
  float mx = blk_max_(lg, rbuf, 4);
  float se = blk_sum_(expf(lg - mx), rbuf, 4);
  if (tid == 0) clse[j] = mx + logf(se);
}

// ---------------- per-batch sim + mutual-NN unit loss (512 thr, K-split) ----------------
__global__ __launch_bounds__(512) void k_unit_sim(
    const float* __restrict__ vpp, const float* __restrict__ tpp,
    const float* __restrict__ lsc, float* __restrict__ simout,
    float* __restrict__ up, float* __restrict__ uc) {
  __shared__ float Sp[2][64][81];
  __shared__ float lse_r[64];
  __shared__ int bestt[64];
  __shared__ float lse_c[80];
  __shared__ int bestv[80];
  __shared__ float rbuf[8];
  const int b = blockIdx.x;
  const int tid = threadIdx.x;
  const int w = tid >> 6, lane = tid & 63;
  const int wq = w >> 1, kg = w & 1;
  const int hi = lane >> 4, lo = lane & 15;
  const float scale = fminf(expf(lsc[0]), 100.f);

  f32x4 acc[5];
  #pragma unroll
  for (int ct = 0; ct < 5; ++ct) acc[ct] = (f32x4){0.f, 0.f, 0.f, 0.f};

  const float* va = vpp + ((size_t)b * 64 + wq * 16 + lo) * 512 + kg * 256;
  const float* tbase = tpp + (size_t)b * 77 * 512 + kg * 256;
  for (int k0 = 0; k0 < 256; k0 += 32) {
    float4 f0 = *(const float4*)(va + k0 + hi * 8);
    float4 f1 = *(const float4*)(va + k0 + hi * 8 + 4);
    short8 a = {f2bf(f0.x), f2bf(f0.y), f2bf(f0.z), f2bf(f0.w),
                f2bf(f1.x), f2bf(f1.y), f2bf(f1.z), f2bf(f1.w)};
    #pragma unroll
    for (int ct = 0; ct < 5; ++ct) {
      int rj = ct * 16 + lo;
      short8 bb = {0, 0, 0, 0, 0, 0, 0, 0};
      if (rj < 77) {
        const float* tb = tbase + (size_t)rj * 512 + k0 + hi * 8;
        float4 g0 = *(const float4*)tb;
        float4 g1 = *(const float4*)(tb + 4);
        bb = (short8){f2bf(g0.x), f2bf(g0.y), f2bf(g0.z), f2bf(g0.w),
                      f2bf(g1.x), f2bf(g1.y), f2bf(g1.z), f2bf(g1.w)};
      }
      acc[ct] = __builtin_amdgcn_mfma_f32_16x16x32_bf16(a, bb, acc[ct], 0, 0, 0);
    }
  }
  #pragma unroll
  for (int ct = 0; ct < 5; ++ct)
    #pragma unroll
    for (int r = 0; r < 4; ++r) {
      int i = wq * 16 + hi * 4 + r, j = ct * 16 + lo;
      if (j < 77) Sp[kg][i][j] = acc[ct][r];
    }
  __syncthreads();
  for (int idx = tid; idx < 64 * 77; idx += 512) {
    int i = idx / 77, j = idx - i * 77;
    float s = Sp[0][i][j] + Sp[1][i][j];
    simout[((size_t)b * 64 + i) * 77 + j] = s;
    Sp[0][i][j] = s * scale;
  }
  __syncthreads();
  if (tid < 64) {
    float mx = -1e30f; int am = 0;
    for (int t = 0; t < 77; ++t) { float x = Sp[0][tid][t]; if (x > mx) { mx = x; am = t; } }
    float se = 0.f;
    for (int t = 0; t < 77; ++t) se += expf(Sp[0][tid][t] - mx);
    lse_r[tid] = mx + logf(se); bestt[tid] = am;
  } else if (tid < 64 + 77) {
    int t = tid - 64;
    float mx = -1e30f; int am = 0;
    for (int v = 0; v < 64; ++v) { float x = Sp[0][v][t]; if (x > mx) { mx = x; am = v; } }
    float se = 0.f;
    for (int v = 0; v < 64; ++v) se += expf(Sp[0][v][t] - mx);
    lse_c[t] = mx + logf(se); bestv[t] = am;
  }
  __syncthreads();
  float c = 0.f, cnt = 0.f;
  if (tid < 64) {
    int j = bestt[tid];
    if (bestv[j] == tid) {
      float sv = Sp[0][tid][j];
      c = -((sv - lse_r[tid]) + (sv - lse_c[j]));
      cnt = 2.f;
    }
  }
  c = blk_sum_(c, rbuf, 8);
  cnt = blk_sum_(cnt, rbuf, 8);
  if (tid == 0) { up[b] = c; uc[b] = cnt; }
}

// ---------------- final scalar losses ----------------
__global__ __launch_bounds__(256) void k_final(
    const float* __restrict__ diag, const float* __restrict__ rlse,
    const float* __restrict__ clse, const float* __restrict__ up,
    const float* __restrict__ uc, const float* __restrict__ part,
    float* __restrict__ out) {
  __shared__ float rbuf[4];
  const int tid = threadIdx.x;
  float d = diag[tid];
  float s1 = blk_sum_(d - rlse[tid], rbuf, 4);
  float s2 = blk_sum_(d - clse[tid], rbuf, 4);
  float su = blk_sum_(up[tid], rbuf, 4);
  float sc = blk_sum_(uc[tid], rbuf, 4);
  float sv = blk_sum_(part[tid], rbuf, 4);
  float st = blk_sum_(part[tid + 256], rbuf, 4);
  if (tid == 0) {
    out[0] = -(s1 * (1.f / 256.f) + s2 * (1.f / 256.f)) * 0.5f;
    out[1] = su / fmaxf(sc, 1.f);
    out[2] = (sv / (256.f * 64.f * 63.f) + st / (256.f * 77.f * 76.f)) * 0.5f;
  }
}

extern "C" void kernel_launch(void* const* d_in, const int* in_sizes, int n_in,
                              void* d_out, int out_size, void* d_ws, size_t ws_size,
                              hipStream_t stream) {
  const float* vis_units = (const float*)d_in[0];
  const float* txt_units = (const float*)d_in[1];
  const float* vis_cls = (const float*)d_in[2];
  const float* txt_cls = (const float*)d_in[3];
  const float* vW1 = (const float*)d_in[4];
  const float* vb1 = (const float*)d_in[5];
  const float* vg  = (const float*)d_in[6];
  const float* vbt = (const float*)d_in[7];
  const float* vW2 = (const float*)d_in[8];
  const float* vb2 = (const float*)d_in[9];
  const float* tW1 = (const float*)d_in[10];
  const float* tb1 = (const float*)d_in[11];
  const float* tg  = (const float*)d_in[12];
  const float* tbt = (const float*)d_in[13];
  const float* tW2 = (const float*)d_in[14];
  const float* tb2 = (const float*)d_in[15];
  const float* gvW = (const float*)d_in[16];
  const float* gvb = (const float*)d_in[17];
  const float* gvg = (const float*)d_in[18];
  const float* gvbt = (const float*)d_in[19];
  const float* gtW = (const float*)d_in[20];
  const float* gtb = (const float*)d_in[21];
  const float* gtg = (const float*)d_in[22];
  const float* gtbt = (const float*)d_in[23];
  const float* lsc = (const float*)d_in[24];

  float* out = (float*)d_out;
  char* ws = (char*)d_ws;
  short* vW1T = (short*)(ws + WS_VW1T);
  short* vW2T = (short*)(ws + WS_VW2T);
  short* tW1T = (short*)(ws + WS_TW1T);
  short* tW2T = (short*)(ws + WS_TW2T);
  short* gvWT = (short*)(ws + WS_GVWT);
  short* gtWT = (short*)(ws + WS_GTWT);
  float* logits = (float*)(ws + WS_LOG);
  float* diag = (float*)(ws + WS_DIAG);
  float* rlse = (float*)(ws + WS_RLSE);
  float* clse = (float*)(ws + WS_CLSE);
  float* up = (float*)(ws + WS_UP);
  float* uc = (float*)(ws + WS_UC);
  float* part = (float*)(ws + WS_PART);
  float* Tt = (float*)(ws + WS_TT);
  float* logitsT = (float*)(ws + WS_LOGT);

  // merged prep (weight fragment cvt + global-proj transposes)
  k_prep<<<3072, 256, 0, stream>>>(vW1, vW2, tW1, tW2, vW1T, vW2T, tW1T, tW2T,
                                   gvW, gvWT, gtW, gtWT);

  // mega: unit MLPs (+fused vis diversity) + txt diversity + global projections
  k_mega<<<1204, 1024, 0, stream>>>(
      vis_units, txt_units,
      vW1T, vb1, vg, vbt, vW2T, vb2,
      tW1T, tb1, tg, tbt, tW2T, tb2,
      out + O_VP, out + O_TP,
      vis_cls, txt_cls,
      gvWT, gvb, gvg, gvbt, gtWT, gtb, gtg, gtbt,
      out + O_VG, out + O_TG, Tt, part);

  // global CLIP loss pieces
  k_logits_row<<<256, 256, 0, stream>>>(out + O_VG, Tt, lsc, logits, logitsT, diag, rlse);
  k_logits_col<<<256, 256, 0, stream>>>(logitsT, clse);

  // unit sim + mutual-NN loss partials (+ sim_matrix output)
  k_unit_sim<<<256, 512, 0, stream>>>(out + O_VP, out + O_TP, lsc, out + O_SM, up, uc);

  // final scalars
  k_final<<<1, 256, 0, stream>>>(diag, rlse, clse, up, uc, part, out);

  (void)in_sizes; (void)n_in; (void)out_size; (void)ws_size;
}

// Round 23
// 218.055 us; speedup vs baseline: 1.0594x; 1.0523x over previous
//
#include <hip/hip_runtime.h>
#include <math.h>

typedef __attribute__((ext_vector_type(8))) short short8;
typedef __attribute__((ext_vector_type(4))) short short4v;
typedef __attribute__((ext_vector_type(4))) float f32x4;

#define NB 256
#define NVU 64
#define NTU 77
#define PD 512

// ---- d_out offsets (in floats) ----
#define O_VP 3ull
#define O_TP (O_VP + (size_t)NB * NVU * PD)
#define O_VG (O_TP + (size_t)NB * NTU * PD)
#define O_TG (O_VG + (size_t)NB * PD)
#define O_SM (O_TG + (size_t)NB * PD)

// ---- ws offsets (bytes) ----
#define WS_VW1T 0u
#define WS_VW2T 524288u
#define WS_TW1T 1048576u
#define WS_TW2T 1572864u
#define WS_GVWT 2097152u
#define WS_GTWT 2883584u
#define WS_LOG  3552256u
#define WS_DIAG 3814400u
#define WS_RLSE 3815424u
#define WS_CLSE 3816448u
#define WS_UP   3817472u
#define WS_UC   3818496u
#define WS_PART 3819520u   // 512 floats -> ends 3821568
#define WS_TT   3821568u   // t_global^T f32[512][256] = 524288
#define WS_LOGT 4345856u   // logits^T f32[256][256] = 262144

// async global->LDS, 16B per lane; LDS dest = wave-uniform base + lane*16
#define GL_LDS16(gp, lp) __builtin_amdgcn_global_load_lds( \
    (const __attribute__((address_space(1))) void*)(gp), \
    (__attribute__((address_space(3))) void*)(lp), 16, 0, 0)

__device__ inline short f2bf(float f) {
  union { float f; unsigned u; } v; v.f = f;
  unsigned r = v.u + 0x7FFFu + ((v.u >> 16) & 1u);   // RNE
  return (short)(r >> 16);
}
__device__ inline float bf2f(short s) {
  union { unsigned u; float f; } v; v.u = ((unsigned)(unsigned short)s) << 16;
  return v.f;
}

__device__ inline float blk_sum_(float x, float* buf, int nw) {
  const int lane = threadIdx.x & 63, w = threadIdx.x >> 6;
  #pragma unroll
  for (int m = 1; m < 64; m <<= 1) x += __shfl_xor(x, m, 64);
  __syncthreads();
  if (lane == 0) buf[w] = x;
  __syncthreads();
  float s = 0.f;
  for (int i = 0; i < nw; ++i) s += buf[i];
  return s;
}
__device__ inline float blk_max_(float x, float* buf, int nw) {
  const int lane = threadIdx.x & 63, w = threadIdx.x >> 6;
  #pragma unroll
  for (int m = 1; m < 64; m <<= 1) x = fmaxf(x, __shfl_xor(x, m, 64));
  __syncthreads();
  if (lane == 0) buf[w] = x;
  __syncthreads();
  float s = buf[0];
  for (int i = 1; i < nw; ++i) s = fmaxf(s, buf[i]);
  return s;
}

// ---------------- merged prep: unit-weight fragment cvt (bids 0..511) +
//                  global-proj transposes (bids 512..3071) ----------------
__global__ __launch_bounds__(256) void k_prep(
    const float* __restrict__ s0, const float* __restrict__ s1,
    const float* __restrict__ s2, const float* __restrict__ s3,
    short* __restrict__ d0, short* __restrict__ d1,
    short* __restrict__ d2, short* __restrict__ d3,
    const float* __restrict__ gv, short* __restrict__ dv_,
    const float* __restrict__ gt, short* __restrict__ dt_) {
  __shared__ short tile[32][66];
  const int bid = blockIdx.x;
  if (bid < 512) {
    const int m = bid >> 7;
    const float* src = m == 0 ? s0 : m == 1 ? s1 : m == 2 ? s2 : s3;
    short* dst = m == 0 ? d0 : m == 1 ? d1 : m == 2 ? d2 : d3;
    const int rem = bid & 127;
    const int kc = rem >> 3, nt = rem & 7;
    const int n0 = nt * 64;
    #pragma unroll
    for (int it = 0; it < 8; ++it) {
      int idx = it * 256 + threadIdx.x;
      int r = idx >> 6, c = idx & 63;
      tile[r][c] = f2bf(src[(size_t)(kc * 32 + r) * 512 + n0 + c]);
    }
    __syncthreads();
    const int nl = threadIdx.x >> 2, s = threadIdx.x & 3;
    const int n = n0 + nl;
    short8 v;
    #pragma unroll
    for (int j = 0; j < 8; ++j) v[j] = tile[s * 8 + j][nl];
    *(short8*)&dst[(size_t)kc * 16384 + n * 32 + ((s ^ ((n >> 1) & 3)) << 3)] = v;
  } else if (bid < 2048) {
    int idx = (bid - 512) * 256 + threadIdx.x;      // 768*512
    int k = idx >> 9, n = idx & 511;
    dv_[(size_t)n * 768 + k] = f2bf(gv[idx]);
  } else {
    int idx = (bid - 2048) * 256 + threadIdx.x;     // 512*512
    int k = idx >> 9, n = idx & 511;
    dt_[(size_t)n * 512 + k] = f2bf(gt[idx]);
  }
}

// ---------------- mega kernel: mlp+vis-div (0..563) + txt-div (564..691) + gproj (692..1203) ----
__global__ __launch_bounds__(1024) void k_mega(
    const float* __restrict__ Xv, const float* __restrict__ Xt,
    const short* __restrict__ vWf1, const float* __restrict__ vb1,
    const float* __restrict__ vg, const float* __restrict__ vbt,
    const short* __restrict__ vWf2, const float* __restrict__ vb2,
    const short* __restrict__ tWf1, const float* __restrict__ tb1,
    const float* __restrict__ tg, const float* __restrict__ tbt,
    const short* __restrict__ tWf2, const float* __restrict__ tb2,
    float* __restrict__ outV, float* __restrict__ outT,
    const float* __restrict__ vsrc, const float* __restrict__ tsrc,
    const short* __restrict__ gvWT, const float* __restrict__ gvb,
    const float* __restrict__ gvg, const float* __restrict__ gvbt,
    const short* __restrict__ gtWT, const float* __restrict__ gtb,
    const float* __restrict__ gtg, const float* __restrict__ gtbt,
    float* __restrict__ outVG, float* __restrict__ outTG,
    float* __restrict__ Tt, float* __restrict__ part) {
  __shared__ __align__(16) short As[64][520];      // 66560 B
  __shared__ __align__(16) short Bs[2][16384];     // 65536 B
  __shared__ float redS[4][64];
  __shared__ float redQ[4][64];

  const int tid = threadIdx.x;
  const int w = tid >> 6, lane = tid & 63;
  const int hi = lane >> 4, lo = lane & 15;
  const int bid = blockIdx.x;

  if (bid < 564) {
    // ================= unit MLP (r15 structure) + fused vis diversity =================
    const int rg = w >> 2, cg = w & 3;
    // bijective XCD swizzle for 564 = 8*70 + 4 (m204)
    const int xcd = bid & 7, ii = bid >> 3;
    const int orig = (xcd < 4 ? xcd * 71 : 284 + (xcd - 4) * 70) + ii;
    const bool isv = orig < 256;
    const int rb = isv ? orig : orig - 256;
    const float* __restrict__ X   = isv ? Xv : Xt;
    const short* __restrict__ Wf1 = isv ? vWf1 : tWf1;
    const float* __restrict__ b1  = isv ? vb1  : tb1;
    const float* __restrict__ gg  = isv ? vg   : tg;
    const float* __restrict__ bt  = isv ? vbt  : tbt;
    const short* __restrict__ Wf2 = isv ? vWf2 : tWf2;
    const float* __restrict__ b2  = isv ? vb2  : tb2;
    float* __restrict__ outF      = isv ? outV : outT;
    const size_t row0 = (size_t)rb * 64;

    const int arow = rg * 16 + lo;
    const int bswz = (cg * 128 + lo) * 32 + ((hi ^ ((lo >> 1) & 3)) * 8);

    GL_LDS16(Wf1 + tid * 8, &Bs[0][tid * 8]);
    GL_LDS16(Wf1 + 8192 + tid * 8, &Bs[0][8192 + tid * 8]);

    const f32x4* Xp = (const f32x4*)(X + row0 * 512);
    #pragma unroll
    for (int i = 0; i < 8; ++i) {
      int idx = i * 1024 + tid;
      f32x4 f = __builtin_nontemporal_load(Xp + idx);
      short4v s4 = {f2bf(f[0]), f2bf(f[1]), f2bf(f[2]), f2bf(f[3])};
      *(short4v*)&As[idx >> 7][(idx & 127) * 4] = s4;
    }
    __syncthreads();   // X + W1 chunk 0 resident

    // issue W1 chunk 1 (2 in flight)
    GL_LDS16(Wf1 + 16384 + tid * 8, &Bs[1][tid * 8]);
    GL_LDS16(Wf1 + 16384 + 8192 + tid * 8, &Bs[1][8192 + tid * 8]);

    if (isv) {
      // ---- fused vis-diversity gram on raw X tile (batch rb == 64 rows) ----
      const int ti = rg, tj = cg;
      f32x4 g = (f32x4){0.f, 0.f, 0.f, 0.f};
      for (int kc = 0; kc < 16; ++kc) {
        short8 ga = *(const short8*)&As[ti * 16 + lo][kc * 32 + hi * 8];
        short8 gb = *(const short8*)&As[tj * 16 + lo][kc * 32 + hi * 8];
        g = __builtin_amdgcn_mfma_f32_16x16x32_bf16(ga, gb, g, 0, 0, 0);
      }
      float* invs = &redQ[0][0];
      if (ti == tj && (lo >> 2) == hi)
        invs[ti * 16 + lo] = 1.f / fmaxf(sqrtf(fmaxf(g[lo & 3], 0.f)), 1e-12f);
      __syncthreads();
      float cs = 0.f;
      #pragma unroll
      for (int r = 0; r < 4; ++r) {
        int i = ti * 16 + hi * 4 + r, j = tj * 16 + lo;
        if (i != j) cs += fabsf(g[r]) * invs[i] * invs[j];
      }
      #pragma unroll
      for (int m = 1; m < 64; m <<= 1) cs += __shfl_xor(cs, m, 64);
      if (lane == 0) redS[0][w] = cs;
      __syncthreads();
      if (tid == 0) {
        float s = 0.f;
        #pragma unroll
        for (int i = 0; i < 16; ++i) s += redS[0][i];
        part[rb] = s;
      }
    }

    f32x4 acc[8];
    #pragma unroll
    for (int ct = 0; ct < 8; ++ct) acc[ct] = (f32x4){0.f, 0.f, 0.f, 0.f};

    for (int kc = 0; kc < 16; ++kc) {
      const int cur = kc & 1;
      short8 a = *(const short8*)&As[arow][kc * 32 + hi * 8];
      #pragma unroll
      for (int ct = 0; ct < 8; ++ct) {
        short8 bb = *(const short8*)&Bs[cur][bswz + ct * 512];
        acc[ct] = __builtin_amdgcn_mfma_f32_16x16x32_bf16(a, bb, acc[ct], 0, 0, 0);
      }
      __builtin_amdgcn_s_barrier();
      const int nc = kc + 2;
      const short* nxt = (nc < 16) ? (Wf1 + (size_t)nc * 16384)
                                   : (Wf2 + (size_t)(nc - 16) * 16384);
      GL_LDS16(nxt + tid * 8, &Bs[cur][tid * 8]);
      GL_LDS16(nxt + 8192 + tid * 8, &Bs[cur][8192 + tid * 8]);
      asm volatile("s_waitcnt vmcnt(2)" ::: "memory");
    }

    {
      float ps[4] = {0.f, 0.f, 0.f, 0.f}, pq[4] = {0.f, 0.f, 0.f, 0.f};
      #pragma unroll
      for (int ct = 0; ct < 8; ++ct) {
        float bia = b1[cg * 128 + ct * 16 + lo];
        #pragma unroll
        for (int r = 0; r < 4; ++r) {
          float v = acc[ct][r] + bia;
          acc[ct][r] = v;
          ps[r] += v; pq[r] += v * v;
        }
      }
      #pragma unroll
      for (int m = 1; m < 16; m <<= 1)
        #pragma unroll
        for (int r = 0; r < 4; ++r) {
          ps[r] += __shfl_xor(ps[r], m, 64);
          pq[r] += __shfl_xor(pq[r], m, 64);
        }
      if (lo == 0) {
        #pragma unroll
        for (int r = 0; r < 4; ++r) {
          int rr = rg * 16 + hi * 4 + r;
          redS[cg][rr] = ps[r]; redQ[cg][rr] = pq[r];
        }
      }
    }
    __syncthreads();

    {
      float mu[4], rs[4];
      #pragma unroll
      for (int r = 0; r < 4; ++r) {
        int rr = rg * 16 + hi * 4 + r;
        float s = redS[0][rr] + redS[1][rr] + redS[2][rr] + redS[3][rr];
        float q = redQ[0][rr] + redQ[1][rr] + redQ[2][rr] + redQ[3][rr];
        float m_ = s * (1.f / 512.f);
        mu[r] = m_;
        rs[r] = rsqrtf(q * (1.f / 512.f) - m_ * m_ + 1e-5f);
      }
      #pragma unroll
      for (int ct = 0; ct < 8; ++ct) {
        int col = cg * 128 + ct * 16 + lo;
        float ga = gg[col], be = bt[col];
        #pragma unroll
        for (int r = 0; r < 4; ++r) {
          float xn = (acc[ct][r] - mu[r]) * rs[r] * ga + be;
          float ge = 0.5f * xn * (1.f + erff(xn * 0.70710678118654752f));
          As[rg * 16 + hi * 4 + r][col] = f2bf(ge);
        }
      }
    }
    __syncthreads();

    #pragma unroll
    for (int ct = 0; ct < 8; ++ct) acc[ct] = (f32x4){0.f, 0.f, 0.f, 0.f};
    for (int kc = 0; kc < 16; ++kc) {
      const int cur = kc & 1;
      short8 a = *(const short8*)&As[arow][kc * 32 + hi * 8];
      #pragma unroll
      for (int ct = 0; ct < 8; ++ct) {
        short8 bb = *(const short8*)&Bs[cur][bswz + ct * 512];
        acc[ct] = __builtin_amdgcn_mfma_f32_16x16x32_bf16(a, bb, acc[ct], 0, 0, 0);
      }
      __builtin_amdgcn_s_barrier();
      if (kc < 14) {
        const short* nxt = Wf2 + (size_t)(kc + 2) * 16384;
        GL_LDS16(nxt + tid * 8, &Bs[cur][tid * 8]);
        GL_LDS16(nxt + 8192 + tid * 8, &Bs[cur][8192 + tid * 8]);
        asm volatile("s_waitcnt vmcnt(2)" ::: "memory");
      } else if (kc == 14) {
        asm volatile("s_waitcnt vmcnt(0)" ::: "memory");
      }
    }

    {
      float pq[4] = {0.f, 0.f, 0.f, 0.f};
      #pragma unroll
      for (int ct = 0; ct < 8; ++ct) {
        float bia = b2[cg * 128 + ct * 16 + lo];
        #pragma unroll
        for (int r = 0; r < 4; ++r) {
          float v = acc[ct][r] + bia;
          acc[ct][r] = v;
          pq[r] += v * v;
        }
      }
      #pragma unroll
      for (int m = 1; m < 16; m <<= 1)
        #pragma unroll
        for (int r = 0; r < 4; ++r) pq[r] += __shfl_xor(pq[r], m, 64);
      if (lo == 0) {
        #pragma unroll
        for (int r = 0; r < 4; ++r) redQ[cg][rg * 16 + hi * 4 + r] = pq[r];
      }
    }
    __syncthreads();
    {
      float invn[4];
      #pragma unroll
      for (int r = 0; r < 4; ++r) {
        int rr = rg * 16 + hi * 4 + r;
        float q = redQ[0][rr] + redQ[1][rr] + redQ[2][rr] + redQ[3][rr];
        invn[r] = 1.f / fmaxf(sqrtf(q), 1e-12f);
      }
      #pragma unroll
      for (int ct = 0; ct < 8; ++ct) {
        int col = cg * 128 + ct * 16 + lo;
        #pragma unroll
        for (int r = 0; r < 4; ++r)
          outF[(row0 + rg * 16 + hi * 4 + r) * 512 + col] = acc[ct][r] * invn[r];
      }
    }
  } else if (bid < 692) {
    // ================= txt diversity (2 batches per block; tid<320 for MFMA) ========
    short (*Bsd)[136] = (short(*)[136])&As[0][0];   // 80*136*2 = 21760 B
    float* invs = &redQ[0][0];                       // 80 floats
    float* rbuf5 = &redS[0][0];                      // 5 floats
    const int ri = w * 16 + lo;
    for (int half = 0; half < 2; ++half) {
      const int b = (bid - 564) * 2 + half;          // 0..255
      const float* X = Xt + (size_t)b * NTU * 512;
      f32x4 acc[5];
      #pragma unroll
      for (int ct = 0; ct < 5; ++ct) acc[ct] = (f32x4){0.f, 0.f, 0.f, 0.f};

      for (int c = 0; c < 4; ++c) {
        for (int s5 = tid; s5 < 80 * 32; s5 += 1024) {
          int r = s5 >> 5, cgp = s5 & 31;
          short4v s4 = {0, 0, 0, 0};
          if (r < NTU) {
            float4 f = *(const float4*)(X + (size_t)r * 512 + c * 128 + cgp * 4);
            s4 = (short4v){f2bf(f.x), f2bf(f.y), f2bf(f.z), f2bf(f.w)};
          }
          *(short4v*)&Bsd[r][cgp * 4] = s4;
        }
        __syncthreads();
        if (tid < 320) {
          #pragma unroll
          for (int kc = 0; kc < 4; ++kc) {
            short8 a = *(const short8*)&Bsd[ri][kc * 32 + hi * 8];
            #pragma unroll
            for (int ct = 0; ct < 5; ++ct) {
              short8 bb = *(const short8*)&Bsd[ct * 16 + lo][kc * 32 + hi * 8];
              acc[ct] = __builtin_amdgcn_mfma_f32_16x16x32_bf16(a, bb, acc[ct], 0, 0, 0);
            }
          }
        }
        __syncthreads();
      }

      if (tid < 320) {
        #pragma unroll
        for (int ct = 0; ct < 5; ++ct)
          #pragma unroll
          for (int r = 0; r < 4; ++r) {
            int i = w * 16 + hi * 4 + r, j = ct * 16 + lo;
            if (i == j && i < NTU) invs[i] = 1.f / fmaxf(sqrtf(fmaxf(acc[ct][r], 0.f)), 1e-12f);
          }
      }
      __syncthreads();

      float cs = 0.f;
      if (tid < 320) {
        #pragma unroll
        for (int ct = 0; ct < 5; ++ct)
          #pragma unroll
          for (int r = 0; r < 4; ++r) {
            int i = w * 16 + hi * 4 + r, j = ct * 16 + lo;
            if (i < NTU && j < NTU && i != j)
              cs += fabsf(acc[ct][r]) * invs[i] * invs[j];
          }
      }
      #pragma unroll
      for (int m = 1; m < 64; m <<= 1) cs += __shfl_xor(cs, m, 64);
      if (lane == 0 && w < 5) rbuf5[w] = cs;
      __syncthreads();
      if (tid == 0) {
        float s = 0.f;
        for (int i = 0; i < 5; ++i) s += rbuf5[i];
        part[256 + b] = s;
      }
      __syncthreads();   // rbuf5/invs free before next half
    }
  } else {
    // ================= global projection (1 row per block; tid<256 active) =========
    float* srow = (float*)&As[0][0];
    float* rb = &redS[0][0];
    const int row = bid - 692;            // 0..511
    const bool isv = row < 256;
    const int r2 = row & 255;
    const int K = isv ? 768 : 512;
    const float* src = isv ? vsrc : tsrc;
    const short* WT = isv ? gvWT : gtWT;
    const float* bias = isv ? gvb : gtb;
    const float* gg = isv ? gvg : gtg;
    const float* bt = isv ? gvbt : gtbt;
    float* outp = isv ? outVG : outTG;
    const bool act = tid < 256;

    for (int k = tid; k < K; k += 1024) srow[k] = src[(size_t)r2 * K + k];
    __syncthreads();
    float v0 = 0.f, v1 = 0.f;
    if (act) {
      const short* wp0 = WT + (size_t)tid * K;
      const short* wp1 = WT + (size_t)(tid + 256) * K;
      for (int k = 0; k < K; k += 8) {
        short8 wa = *(const short8*)(wp0 + k);
        short8 wb = *(const short8*)(wp1 + k);
        #pragma unroll
        for (int j = 0; j < 8; ++j) {
          float sv = srow[k + j];
          v0 += sv * bf2f(wa[j]);
          v1 += sv * bf2f(wb[j]);
        }
      }
      v0 += bias[tid]; v1 += bias[tid + 256];
    }
    float s = act ? (v0 + v1) : 0.f;
    float q = act ? (v0 * v0 + v1 * v1) : 0.f;
    #pragma unroll
    for (int m = 1; m < 64; m <<= 1) {
      s += __shfl_xor(s, m, 64);
      q += __shfl_xor(q, m, 64);
    }
    if (lane == 0 && w < 4) { rb[w] = s; rb[4 + w] = q; }
    __syncthreads();
    s = rb[0] + rb[1] + rb[2] + rb[3];
    q = rb[4] + rb[5] + rb[6] + rb[7];
    __syncthreads();
    float mu = s * (1.f / 512.f);
    float var = q * (1.f / 512.f) - mu * mu;
    float rs = rsqrtf(var + 1e-5f);
    float y0 = 0.f, y1 = 0.f;
    if (act) {
      y0 = (v0 - mu) * rs * gg[tid] + bt[tid];
      y1 = (v1 - mu) * rs * gg[tid + 256] + bt[tid + 256];
    }
    float ss = act ? (y0 * y0 + y1 * y1) : 0.f;
    #pragma unroll
    for (int m = 1; m < 64; m <<= 1) ss += __shfl_xor(ss, m, 64);
    if (lane == 0 && w < 4) rb[w] = ss;
    __syncthreads();
    ss = rb[0] + rb[1] + rb[2] + rb[3];
    float invn = 1.f / fmaxf(sqrtf(ss), 1e-12f);
    if (act) {
      float o0 = y0 * invn, o1 = y1 * invn;
      outp[(size_t)r2 * 512 + tid] = o0;
      outp[(size_t)r2 * 512 + tid + 256] = o1;
      if (!isv) {
        Tt[(size_t)tid * 256 + r2] = o0;
        Tt[(size_t)(tid + 256) * 256 + r2] = o1;
      }
    }
  }
}

// ---------------- mega2: unit_sim (0..255) + logits_row (256..511), 512 thr ----------------
__global__ __launch_bounds__(512) void k_mega2(
    const float* __restrict__ vpp, const float* __restrict__ tpp,
    const float* __restrict__ lsc, float* __restrict__ simout,
    float* __restrict__ up, float* __restrict__ uc,
    const float* __restrict__ vgp, const float* __restrict__ Tt,
    float* __restrict__ logits, float* __restrict__ logitsT,
    float* __restrict__ diag, float* __restrict__ rlse) {
  __shared__ float Sp[2][64][81];
  __shared__ float lse_r[64];
  __shared__ int bestt[64];
  __shared__ float lse_c[80];
  __shared__ int bestv[80];
  __shared__ float rbuf[8];
  const int tid = threadIdx.x;
  const int w = tid >> 6, lane = tid & 63;
  const int hi = lane >> 4, lo = lane & 15;
  const float scale = fminf(expf(lsc[0]), 100.f);

  if (blockIdx.x < 256) {
    // ================= per-batch sim + mutual-NN unit loss =================
    const int b = blockIdx.x;
    const int wq = w >> 1, kg = w & 1;

    f32x4 acc[5];
    #pragma unroll
    for (int ct = 0; ct < 5; ++ct) acc[ct] = (f32x4){0.f, 0.f, 0.f, 0.f};

    const float* va = vpp + ((size_t)b * 64 + wq * 16 + lo) * 512 + kg * 256;
    const float* tbase = tpp + (size_t)b * 77 * 512 + kg * 256;
    for (int k0 = 0; k0 < 256; k0 += 32) {
      float4 f0 = *(const float4*)(va + k0 + hi * 8);
      float4 f1 = *(const float4*)(va + k0 + hi * 8 + 4);
      short8 a = {f2bf(f0.x), f2bf(f0.y), f2bf(f0.z), f2bf(f0.w),
                  f2bf(f1.x), f2bf(f1.y), f2bf(f1.z), f2bf(f1.w)};
      #pragma unroll
      for (int ct = 0; ct < 5; ++ct) {
        int rj = ct * 16 + lo;
        short8 bb = {0, 0, 0, 0, 0, 0, 0, 0};
        if (rj < 77) {
          const float* tb = tbase + (size_t)rj * 512 + k0 + hi * 8;
          float4 g0 = *(const float4*)tb;
          float4 g1 = *(const float4*)(tb + 4);
          bb = (short8){f2bf(g0.x), f2bf(g0.y), f2bf(g0.z), f2bf(g0.w),
                        f2bf(g1.x), f2bf(g1.y), f2bf(g1.z), f2bf(g1.w)};
        }
        acc[ct] = __builtin_amdgcn_mfma_f32_16x16x32_bf16(a, bb, acc[ct], 0, 0, 0);
      }
    }
    #pragma unroll
    for (int ct = 0; ct < 5; ++ct)
      #pragma unroll
      for (int r = 0; r < 4; ++r) {
        int i = wq * 16 + hi * 4 + r, j = ct * 16 + lo;
        if (j < 77) Sp[kg][i][j] = acc[ct][r];
      }
    __syncthreads();
    for (int idx = tid; idx < 64 * 77; idx += 512) {
      int i = idx / 77, j = idx - i * 77;
      float s = Sp[0][i][j] + Sp[1][i][j];
      simout[((size_t)b * 64 + i) * 77 + j] = s;
      Sp[0][i][j] = s * scale;
    }
    __syncthreads();
    if (tid < 64) {
      float mx = -1e30f; int am = 0;
      for (int t = 0; t < 77; ++t) { float x = Sp[0][tid][t]; if (x > mx) { mx = x; am = t; } }
      float se = 0.f;
      for (int t = 0; t < 77; ++t) se += expf(Sp[0][tid][t] - mx);
      lse_r[tid] = mx + logf(se); bestt[tid] = am;
    } else if (tid < 64 + 77) {
      int t = tid - 64;
      float mx = -1e30f; int am = 0;
      for (int v = 0; v < 64; ++v) { float x = Sp[0][v][t]; if (x > mx) { mx = x; am = v; } }
      float se = 0.f;
      for (int v = 0; v < 64; ++v) se += expf(Sp[0][v][t] - mx);
      lse_c[t] = mx + logf(se); bestv[t] = am;
    }
    __syncthreads();
    float c = 0.f, cnt = 0.f;
    if (tid < 64) {
      int j = bestt[tid];
      if (bestv[j] == tid) {
        float sv = Sp[0][tid][j];
        c = -((sv - lse_r[tid]) + (sv - lse_c[j]));
        cnt = 2.f;
      }
    }
    c = blk_sum_(c, rbuf, 8);
    cnt = blk_sum_(cnt, rbuf, 8);
    if (tid == 0) { up[b] = c; uc[b] = cnt; }
  } else {
    // ================= logits row (i = bid-256), tid<256 active =================
    float* vrow = &Sp[0][0][0];              // 512 floats (aliased)
    const int i = blockIdx.x - 256;
    vrow[tid] = vgp[(size_t)i * 512 + tid];  // 512 threads load 512 elems
    __syncthreads();
    float lg = -1e30f;
    if (tid < 256) {
      float s = 0.f;
      #pragma unroll 8
      for (int k = 0; k < 512; ++k)
        s += vrow[k] * Tt[(size_t)k * 256 + tid];
      lg = scale * s;
      logits[(size_t)i * 256 + tid] = lg;
      logitsT[(size_t)tid * 256 + i] = lg;
      if (tid == i) diag[i] = lg;
    }
    float mx = blk_max_(lg, rbuf, 8);
    float se = blk_sum_(tid < 256 ? expf(lg - mx) : 0.f, rbuf, 8);
    if (tid == 0) rlse[i] = mx + logf(se);
  }
}

// ---------------- logits cols: coalesced via logits^T ----------------
__global__ __launch_bounds__(256) void k_logits_col(
    const float* __restrict__ logitsT, float* __restrict__ clse) {
  __shared__ float rbuf[4];
  const int j = blockIdx.x, tid = threadIdx.x;
  float lg = logitsT[(size_t)j * 256 + tid];
  float mx = blk_max_(lg, rbuf, 4);
  float se = blk_sum_(expf(lg - mx), rbuf, 4);
  if (tid == 0) clse[j] = mx + logf(se);
}

// ---------------- final scalar losses ----------------
__global__ __launch_bounds__(256) void k_final(
    const float* __restrict__ diag, const float* __restrict__ rlse,
    const float* __restrict__ clse, const float* __restrict__ up,
    const float* __restrict__ uc, const float* __restrict__ part,
    float* __restrict__ out) {
  __shared__ float rbuf[4];
  const int tid = threadIdx.x;
  float d = diag[tid];
  float s1 = blk_sum_(d - rlse[tid], rbuf, 4);
  float s2 = blk_sum_(d - clse[tid], rbuf, 4);
  float su = blk_sum_(up[tid], rbuf, 4);
  float sc = blk_sum_(uc[tid], rbuf, 4);
  float sv = blk_sum_(part[tid], rbuf, 4);
  float st = blk_sum_(part[tid + 256], rbuf, 4);
  if (tid == 0) {
    out[0] = -(s1 * (1.f / 256.f) + s2 * (1.f / 256.f)) * 0.5f;
    out[1] = su / fmaxf(sc, 1.f);
    out[2] = (sv / (256.f * 64.f * 63.f) + st / (256.f * 77.f * 76.f)) * 0.5f;
  }
}

extern "C" void kernel_launch(void* const* d_in, const int* in_sizes, int n_in,
                              void* d_out, int out_size, void* d_ws, size_t ws_size,
                              hipStream_t stream) {
  const float* vis_units = (const float*)d_in[0];
  const float* txt_units = (const float*)d_in[1];
  const float* vis_cls = (const float*)d_in[2];
  const float* txt_cls = (const float*)d_in[3];
  const float* vW1 = (const float*)d_in[4];
  const float* vb1 = (const float*)d_in[5];
  const float* vg  = (const float*)d_in[6];
  const float* vbt = (const float*)d_in[7];
  const float* vW2 = (const float*)d_in[8];
  const float* vb2 = (const float*)d_in[9];
  const float* tW1 = (const float*)d_in[10];
  const float* tb1 = (const float*)d_in[11];
  const float* tg  = (const float*)d_in[12];
  const float* tbt = (const float*)d_in[13];
  const float* tW2 = (const float*)d_in[14];
  const float* tb2 = (const float*)d_in[15];
  const float* gvW = (const float*)d_in[16];
  const float* gvb = (const float*)d_in[17];
  const float* gvg = (const float*)d_in[18];
  const float* gvbt = (const float*)d_in[19];
  const float* gtW = (const float*)d_in[20];
  const float* gtb = (const float*)d_in[21];
  const float* gtg = (const float*)d_in[22];
  const float* gtbt = (const float*)d_in[23];
  const float* lsc = (const float*)d_in[24];

  float* out = (float*)d_out;
  char* ws = (char*)d_ws;
  short* vW1T = (short*)(ws + WS_VW1T);
  short* vW2T = (short*)(ws + WS_VW2T);
  short* tW1T = (short*)(ws + WS_TW1T);
  short* tW2T = (short*)(ws + WS_TW2T);
  short* gvWT = (short*)(ws + WS_GVWT);
  short* gtWT = (short*)(ws + WS_GTWT);
  float* logits = (float*)(ws + WS_LOG);
  float* diag = (float*)(ws + WS_DIAG);
  float* rlse = (float*)(ws + WS_RLSE);
  float* clse = (float*)(ws + WS_CLSE);
  float* up = (float*)(ws + WS_UP);
  float* uc = (float*)(ws + WS_UC);
  float* part = (float*)(ws + WS_PART);
  float* Tt = (float*)(ws + WS_TT);
  float* logitsT = (float*)(ws + WS_LOGT);

  // merged prep (weight fragment cvt + global-proj transposes)
  k_prep<<<3072, 256, 0, stream>>>(vW1, vW2, tW1, tW2, vW1T, vW2T, tW1T, tW2T,
                                   gvW, gvWT, gtW, gtWT);

  // mega: unit MLPs (+fused vis diversity) + txt diversity + global projections
  k_mega<<<1204, 1024, 0, stream>>>(
      vis_units, txt_units,
      vW1T, vb1, vg, vbt, vW2T, vb2,
      tW1T, tb1, tg, tbt, tW2T, tb2,
      out + O_VP, out + O_TP,
      vis_cls, txt_cls,
      gvWT, gvb, gvg, gvbt, gtWT, gtb, gtg, gtbt,
      out + O_VG, out + O_TG, Tt, part);

  // mega2: unit sim + logits rows (independent, co-scheduled)
  k_mega2<<<512, 512, 0, stream>>>(
      out + O_VP, out + O_TP, lsc, out + O_SM, up, uc,
      out + O_VG, Tt, logits, logitsT, diag, rlse);

  // logits cols
  k_logits_col<<<256, 256, 0, stream>>>(logitsT, clse);

  // final scalars
  k_final<<<1, 256, 0, stream>>>(diag, rlse, clse, up, uc, part, out);

  (void)in_sizes; (void)n_in; (void)out_size; (void)ws_size;
}

// Round 24
// 209.875 us; speedup vs baseline: 1.1007x; 1.0390x over previous
//
#include <hip/hip_runtime.h>
#include <math.h>

typedef __attribute__((ext_vector_type(8))) short short8;
typedef __attribute__((ext_vector_type(4))) short short4v;
typedef __attribute__((ext_vector_type(4))) float f32x4;

#define NB 256
#define NVU 64
#define NTU 77
#define PD 512

// ---- d_out offsets (in floats) ----
#define O_VP 3ull
#define O_TP (O_VP + (size_t)NB * NVU * PD)
#define O_VG (O_TP + (size_t)NB * NTU * PD)
#define O_TG (O_VG + (size_t)NB * PD)
#define O_SM (O_TG + (size_t)NB * PD)

// ---- ws offsets (bytes) ----
#define WS_VW1T 0u
#define WS_VW2T 524288u
#define WS_TW1T 1048576u
#define WS_TW2T 1572864u
#define WS_GVWT 2097152u
#define WS_GTWT 2883584u
#define WS_LOG  3552256u
#define WS_DIAG 3814400u
#define WS_RLSE 3815424u
#define WS_CLSE 3816448u
#define WS_UP   3817472u
#define WS_UC   3818496u
#define WS_PART 3819520u   // 512 floats -> ends 3821568
#define WS_TT   3821568u   // t_global^T f32[512][256] = 524288
#define WS_LOGT 4345856u   // logits^T f32[256][256] = 262144

// async global->LDS, 16B per lane; LDS dest = wave-uniform base + lane*16
#define GL_LDS16(gp, lp) __builtin_amdgcn_global_load_lds( \
    (const __attribute__((address_space(1))) void*)(gp), \
    (__attribute__((address_space(3))) void*)(lp), 16, 0, 0)

__device__ inline short f2bf(float f) {
  union { float f; unsigned u; } v; v.f = f;
  unsigned r = v.u + 0x7FFFu + ((v.u >> 16) & 1u);   // RNE
  return (short)(r >> 16);
}
__device__ inline float bf2f(short s) {
  union { unsigned u; float f; } v; v.u = ((unsigned)(unsigned short)s) << 16;
  return v.f;
}

__device__ inline float blk_sum_(float x, float* buf, int nw) {
  const int lane = threadIdx.x & 63, w = threadIdx.x >> 6;
  #pragma unroll
  for (int m = 1; m < 64; m <<= 1) x += __shfl_xor(x, m, 64);
  __syncthreads();
  if (lane == 0) buf[w] = x;
  __syncthreads();
  float s = 0.f;
  for (int i = 0; i < nw; ++i) s += buf[i];
  return s;
}
__device__ inline float blk_max_(float x, float* buf, int nw) {
  const int lane = threadIdx.x & 63, w = threadIdx.x >> 6;
  #pragma unroll
  for (int m = 1; m < 64; m <<= 1) x = fmaxf(x, __shfl_xor(x, m, 64));
  __syncthreads();
  if (lane == 0) buf[w] = x;
  __syncthreads();
  float s = buf[0];
  for (int i = 1; i < nw; ++i) s = fmaxf(s, buf[i]);
  return s;
}

// ---------------- merged prep: unit-weight fragment cvt (bids 0..511) +
//                  global-proj transposes (bids 512..3071) ----------------
__global__ __launch_bounds__(256) void k_prep(
    const float* __restrict__ s0, const float* __restrict__ s1,
    const float* __restrict__ s2, const float* __restrict__ s3,
    short* __restrict__ d0, short* __restrict__ d1,
    short* __restrict__ d2, short* __restrict__ d3,
    const float* __restrict__ gv, short* __restrict__ dv_,
    const float* __restrict__ gt, short* __restrict__ dt_) {
  __shared__ short tile[32][66];
  const int bid = blockIdx.x;
  if (bid < 512) {
    const int m = bid >> 7;
    const float* src = m == 0 ? s0 : m == 1 ? s1 : m == 2 ? s2 : s3;
    short* dst = m == 0 ? d0 : m == 1 ? d1 : m == 2 ? d2 : d3;
    const int rem = bid & 127;
    const int kc = rem >> 3, nt = rem & 7;
    const int n0 = nt * 64;
    #pragma unroll
    for (int it = 0; it < 8; ++it) {
      int idx = it * 256 + threadIdx.x;
      int r = idx >> 6, c = idx & 63;
      tile[r][c] = f2bf(src[(size_t)(kc * 32 + r) * 512 + n0 + c]);
    }
    __syncthreads();
    const int nl = threadIdx.x >> 2, s = threadIdx.x & 3;
    const int n = n0 + nl;
    short8 v;
    #pragma unroll
    for (int j = 0; j < 8; ++j) v[j] = tile[s * 8 + j][nl];
    *(short8*)&dst[(size_t)kc * 16384 + n * 32 + ((s ^ ((n >> 1) & 3)) << 3)] = v;
  } else if (bid < 2048) {
    int idx = (bid - 512) * 256 + threadIdx.x;      // 768*512
    int k = idx >> 9, n = idx & 511;
    dv_[(size_t)n * 768 + k] = f2bf(gv[idx]);
  } else {
    int idx = (bid - 2048) * 256 + threadIdx.x;     // 512*512
    int k = idx >> 9, n = idx & 511;
    dt_[(size_t)n * 512 + k] = f2bf(gt[idx]);
  }
}

// ---------------- mega kernel: mlp+vis-div (0..563) + txt-div (564..691) + gproj (692..1203) ----
__global__ __launch_bounds__(1024) void k_mega(
    const float* __restrict__ Xv, const float* __restrict__ Xt,
    const short* __restrict__ vWf1, const float* __restrict__ vb1,
    const float* __restrict__ vg, const float* __restrict__ vbt,
    const short* __restrict__ vWf2, const float* __restrict__ vb2,
    const short* __restrict__ tWf1, const float* __restrict__ tb1,
    const float* __restrict__ tg, const float* __restrict__ tbt,
    const short* __restrict__ tWf2, const float* __restrict__ tb2,
    float* __restrict__ outV, float* __restrict__ outT,
    const float* __restrict__ vsrc, const float* __restrict__ tsrc,
    const short* __restrict__ gvWT, const float* __restrict__ gvb,
    const float* __restrict__ gvg, const float* __restrict__ gvbt,
    const short* __restrict__ gtWT, const float* __restrict__ gtb,
    const float* __restrict__ gtg, const float* __restrict__ gtbt,
    float* __restrict__ outVG, float* __restrict__ outTG,
    float* __restrict__ Tt, float* __restrict__ part) {
  __shared__ __align__(16) short As[64][520];      // 66560 B
  __shared__ __align__(16) short Bs[2][16384];     // 65536 B
  __shared__ float redS[4][64];
  __shared__ float redQ[4][64];

  const int tid = threadIdx.x;
  const int w = tid >> 6, lane = tid & 63;
  const int hi = lane >> 4, lo = lane & 15;
  const int bid = blockIdx.x;

  if (bid < 564) {
    // ================= unit MLP (r15 structure) + fused vis diversity =================
    const int rg = w >> 2, cg = w & 3;
    // bijective XCD swizzle for 564 = 8*70 + 4 (m204)
    const int xcd = bid & 7, ii = bid >> 3;
    const int orig = (xcd < 4 ? xcd * 71 : 284 + (xcd - 4) * 70) + ii;
    const bool isv = orig < 256;
    const int rb = isv ? orig : orig - 256;
    const float* __restrict__ X   = isv ? Xv : Xt;
    const short* __restrict__ Wf1 = isv ? vWf1 : tWf1;
    const float* __restrict__ b1  = isv ? vb1  : tb1;
    const float* __restrict__ gg  = isv ? vg   : tg;
    const float* __restrict__ bt  = isv ? vbt  : tbt;
    const short* __restrict__ Wf2 = isv ? vWf2 : tWf2;
    const float* __restrict__ b2  = isv ? vb2  : tb2;
    float* __restrict__ outF      = isv ? outV : outT;
    const size_t row0 = (size_t)rb * 64;

    const int arow = rg * 16 + lo;
    const int bswz = (cg * 128 + lo) * 32 + ((hi ^ ((lo >> 1) & 3)) * 8);

    GL_LDS16(Wf1 + tid * 8, &Bs[0][tid * 8]);
    GL_LDS16(Wf1 + 8192 + tid * 8, &Bs[0][8192 + tid * 8]);

    const f32x4* Xp = (const f32x4*)(X + row0 * 512);
    #pragma unroll
    for (int i = 0; i < 8; ++i) {
      int idx = i * 1024 + tid;
      f32x4 f = __builtin_nontemporal_load(Xp + idx);
      short4v s4 = {f2bf(f[0]), f2bf(f[1]), f2bf(f[2]), f2bf(f[3])};
      *(short4v*)&As[idx >> 7][(idx & 127) * 4] = s4;
    }
    __syncthreads();   // X + W1 chunk 0 resident

    // issue W1 chunk 1 (2 in flight)
    GL_LDS16(Wf1 + 16384 + tid * 8, &Bs[1][tid * 8]);
    GL_LDS16(Wf1 + 16384 + 8192 + tid * 8, &Bs[1][8192 + tid * 8]);

    if (isv) {
      // ---- fused vis-diversity gram on raw X tile (batch rb == 64 rows) ----
      const int ti = rg, tj = cg;
      f32x4 g = (f32x4){0.f, 0.f, 0.f, 0.f};
      for (int kc = 0; kc < 16; ++kc) {
        short8 ga = *(const short8*)&As[ti * 16 + lo][kc * 32 + hi * 8];
        short8 gb = *(const short8*)&As[tj * 16 + lo][kc * 32 + hi * 8];
        g = __builtin_amdgcn_mfma_f32_16x16x32_bf16(ga, gb, g, 0, 0, 0);
      }
      float* invs = &redQ[0][0];
      if (ti == tj && (lo >> 2) == hi)
        invs[ti * 16 + lo] = 1.f / fmaxf(sqrtf(fmaxf(g[lo & 3], 0.f)), 1e-12f);
      __syncthreads();
      float cs = 0.f;
      #pragma unroll
      for (int r = 0; r < 4; ++r) {
        int i = ti * 16 + hi * 4 + r, j = tj * 16 + lo;
        if (i != j) cs += fabsf(g[r]) * invs[i] * invs[j];
      }
      #pragma unroll
      for (int m = 1; m < 64; m <<= 1) cs += __shfl_xor(cs, m, 64);
      if (lane == 0) redS[0][w] = cs;
      __syncthreads();
      if (tid == 0) {
        float s = 0.f;
        #pragma unroll
        for (int i = 0; i < 16; ++i) s += redS[0][i];
        part[rb] = s;
      }
    }

    f32x4 acc[8];
    #pragma unroll
    for (int ct = 0; ct < 8; ++ct) acc[ct] = (f32x4){0.f, 0.f, 0.f, 0.f};

    for (int kc = 0; kc < 16; ++kc) {
      const int cur = kc & 1;
      short8 a = *(const short8*)&As[arow][kc * 32 + hi * 8];
      #pragma unroll
      for (int ct = 0; ct < 8; ++ct) {
        short8 bb = *(const short8*)&Bs[cur][bswz + ct * 512];
        acc[ct] = __builtin_amdgcn_mfma_f32_16x16x32_bf16(a, bb, acc[ct], 0, 0, 0);
      }
      __builtin_amdgcn_s_barrier();
      const int nc = kc + 2;
      const short* nxt = (nc < 16) ? (Wf1 + (size_t)nc * 16384)
                                   : (Wf2 + (size_t)(nc - 16) * 16384);
      GL_LDS16(nxt + tid * 8, &Bs[cur][tid * 8]);
      GL_LDS16(nxt + 8192 + tid * 8, &Bs[cur][8192 + tid * 8]);
      asm volatile("s_waitcnt vmcnt(2)" ::: "memory");
    }

    {
      float ps[4] = {0.f, 0.f, 0.f, 0.f}, pq[4] = {0.f, 0.f, 0.f, 0.f};
      #pragma unroll
      for (int ct = 0; ct < 8; ++ct) {
        float bia = b1[cg * 128 + ct * 16 + lo];
        #pragma unroll
        for (int r = 0; r < 4; ++r) {
          float v = acc[ct][r] + bia;
          acc[ct][r] = v;
          ps[r] += v; pq[r] += v * v;
        }
      }
      #pragma unroll
      for (int m = 1; m < 16; m <<= 1)
        #pragma unroll
        for (int r = 0; r < 4; ++r) {
          ps[r] += __shfl_xor(ps[r], m, 64);
          pq[r] += __shfl_xor(pq[r], m, 64);
        }
      if (lo == 0) {
        #pragma unroll
        for (int r = 0; r < 4; ++r) {
          int rr = rg * 16 + hi * 4 + r;
          redS[cg][rr] = ps[r]; redQ[cg][rr] = pq[r];
        }
      }
    }
    __syncthreads();

    {
      float mu[4], rs[4];
      #pragma unroll
      for (int r = 0; r < 4; ++r) {
        int rr = rg * 16 + hi * 4 + r;
        float s = redS[0][rr] + redS[1][rr] + redS[2][rr] + redS[3][rr];
        float q = redQ[0][rr] + redQ[1][rr] + redQ[2][rr] + redQ[3][rr];
        float m_ = s * (1.f / 512.f);
        mu[r] = m_;
        rs[r] = rsqrtf(q * (1.f / 512.f) - m_ * m_ + 1e-5f);
      }
      #pragma unroll
      for (int ct = 0; ct < 8; ++ct) {
        int col = cg * 128 + ct * 16 + lo;
        float ga = gg[col], be = bt[col];
        #pragma unroll
        for (int r = 0; r < 4; ++r) {
          float xn = (acc[ct][r] - mu[r]) * rs[r] * ga + be;
          float ge = 0.5f * xn * (1.f + erff(xn * 0.70710678118654752f));
          As[rg * 16 + hi * 4 + r][col] = f2bf(ge);
        }
      }
    }
    __syncthreads();

    #pragma unroll
    for (int ct = 0; ct < 8; ++ct) acc[ct] = (f32x4){0.f, 0.f, 0.f, 0.f};
    for (int kc = 0; kc < 16; ++kc) {
      const int cur = kc & 1;
      short8 a = *(const short8*)&As[arow][kc * 32 + hi * 8];
      #pragma unroll
      for (int ct = 0; ct < 8; ++ct) {
        short8 bb = *(const short8*)&Bs[cur][bswz + ct * 512];
        acc[ct] = __builtin_amdgcn_mfma_f32_16x16x32_bf16(a, bb, acc[ct], 0, 0, 0);
      }
      __builtin_amdgcn_s_barrier();
      if (kc < 14) {
        const short* nxt = Wf2 + (size_t)(kc + 2) * 16384;
        GL_LDS16(nxt + tid * 8, &Bs[cur][tid * 8]);
        GL_LDS16(nxt + 8192 + tid * 8, &Bs[cur][8192 + tid * 8]);
        asm volatile("s_waitcnt vmcnt(2)" ::: "memory");
      } else if (kc == 14) {
        asm volatile("s_waitcnt vmcnt(0)" ::: "memory");
      }
    }

    {
      float pq[4] = {0.f, 0.f, 0.f, 0.f};
      #pragma unroll
      for (int ct = 0; ct < 8; ++ct) {
        float bia = b2[cg * 128 + ct * 16 + lo];
        #pragma unroll
        for (int r = 0; r < 4; ++r) {
          float v = acc[ct][r] + bia;
          acc[ct][r] = v;
          pq[r] += v * v;
        }
      }
      #pragma unroll
      for (int m = 1; m < 16; m <<= 1)
        #pragma unroll
        for (int r = 0; r < 4; ++r) pq[r] += __shfl_xor(pq[r], m, 64);
      if (lo == 0) {
        #pragma unroll
        for (int r = 0; r < 4; ++r) redQ[cg][rg * 16 + hi * 4 + r] = pq[r];
      }
    }
    __syncthreads();
    {
      float invn[4];
      #pragma unroll
      for (int r = 0; r < 4; ++r) {
        int rr = rg * 16 + hi * 4 + r;
        float q = redQ[0][rr] + redQ[1][rr] + redQ[2][rr] + redQ[3][rr];
        invn[r] = 1.f / fmaxf(sqrtf(q), 1e-12f);
      }
      #pragma unroll
      for (int ct = 0; ct < 8; ++ct) {
        int col = cg * 128 + ct * 16 + lo;
        #pragma unroll
        for (int r = 0; r < 4; ++r)
          outF[(row0 + rg * 16 + hi * 4 + r) * 512 + col] = acc[ct][r] * invn[r];
      }
    }
  } else if (bid < 692) {
    // ================= txt diversity (2 batches per block; tid<320 for MFMA) ========
    short (*Bsd)[136] = (short(*)[136])&As[0][0];   // 80*136*2 = 21760 B
    float* invs = &redQ[0][0];                       // 80 floats
    float* rbuf5 = &redS[0][0];                      // 5 floats
    const int ri = w * 16 + lo;
    for (int half = 0; half < 2; ++half) {
      const int b = (bid - 564) * 2 + half;          // 0..255
      const float* X = Xt + (size_t)b * NTU * 512;
      f32x4 acc[5];
      #pragma unroll
      for (int ct = 0; ct < 5; ++ct) acc[ct] = (f32x4){0.f, 0.f, 0.f, 0.f};

      for (int c = 0; c < 4; ++c) {
        for (int s5 = tid; s5 < 80 * 32; s5 += 1024) {
          int r = s5 >> 5, cgp = s5 & 31;
          short4v s4 = {0, 0, 0, 0};
          if (r < NTU) {
            float4 f = *(const float4*)(X + (size_t)r * 512 + c * 128 + cgp * 4);
            s4 = (short4v){f2bf(f.x), f2bf(f.y), f2bf(f.z), f2bf(f.w)};
          }
          *(short4v*)&Bsd[r][cgp * 4] = s4;
        }
        __syncthreads();
        if (tid < 320) {
          #pragma unroll
          for (int kc = 0; kc < 4; ++kc) {
            short8 a = *(const short8*)&Bsd[ri][kc * 32 + hi * 8];
            #pragma unroll
            for (int ct = 0; ct < 5; ++ct) {
              short8 bb = *(const short8*)&Bsd[ct * 16 + lo][kc * 32 + hi * 8];
              acc[ct] = __builtin_amdgcn_mfma_f32_16x16x32_bf16(a, bb, acc[ct], 0, 0, 0);
            }
          }
        }
        __syncthreads();
      }

      if (tid < 320) {
        #pragma unroll
        for (int ct = 0; ct < 5; ++ct)
          #pragma unroll
          for (int r = 0; r < 4; ++r) {
            int i = w * 16 + hi * 4 + r, j = ct * 16 + lo;
            if (i == j && i < NTU) invs[i] = 1.f / fmaxf(sqrtf(fmaxf(acc[ct][r], 0.f)), 1e-12f);
          }
      }
      __syncthreads();

      float cs = 0.f;
      if (tid < 320) {
        #pragma unroll
        for (int ct = 0; ct < 5; ++ct)
          #pragma unroll
          for (int r = 0; r < 4; ++r) {
            int i = w * 16 + hi * 4 + r, j = ct * 16 + lo;
            if (i < NTU && j < NTU && i != j)
              cs += fabsf(acc[ct][r]) * invs[i] * invs[j];
          }
      }
      #pragma unroll
      for (int m = 1; m < 64; m <<= 1) cs += __shfl_xor(cs, m, 64);
      if (lane == 0 && w < 5) rbuf5[w] = cs;
      __syncthreads();
      if (tid == 0) {
        float s = 0.f;
        for (int i = 0; i < 5; ++i) s += rbuf5[i];
        part[256 + b] = s;
      }
      __syncthreads();   // rbuf5/invs free before next half
    }
  } else {
    // ========== global projection (1 row per block; 1024 threads, K split in halves) ==========
    float* srow = (float*)&As[0][0];              // 768 floats
    float* partial = (float*)&As[0][0] + 1024;    // 1024 floats (byte offset 4096)
    float* rb = &redS[0][0];                      // 256 floats available
    const int row = bid - 692;            // 0..511
    const bool isv = row < 256;
    const int r2 = row & 255;
    const int K = isv ? 768 : 512;
    const int Kh = K >> 1;
    const float* src = isv ? vsrc : tsrc;
    const short* WT = isv ? gvWT : gtWT;
    const float* bias = isv ? gvb : gtb;
    const float* gg = isv ? gvg : gtg;
    const float* bt = isv ? gvbt : gtbt;
    float* outp = isv ? outVG : outTG;

    for (int k = tid; k < K; k += 1024) srow[k] = src[(size_t)r2 * K + k];
    __syncthreads();
    {
      const int halfk = tid >> 9;                 // 0 or 1
      const int c = tid & 511;                    // column
      const short* wp = WT + (size_t)c * K + halfk * Kh;
      const float* sr = srow + halfk * Kh;
      float v = 0.f;
      for (int k = 0; k < Kh; k += 8) {
        short8 wa = *(const short8*)(wp + k);
        #pragma unroll
        for (int j = 0; j < 8; ++j) v += sr[k + j] * bf2f(wa[j]);
      }
      partial[tid] = v;
    }
    __syncthreads();
    const bool act = tid < 512;
    const int c = tid & 511;
    float v = 0.f;
    if (act) v = partial[c] + partial[512 + c] + bias[c];
    float s = act ? v : 0.f;
    float q = act ? v * v : 0.f;
    #pragma unroll
    for (int m = 1; m < 64; m <<= 1) {
      s += __shfl_xor(s, m, 64);
      q += __shfl_xor(q, m, 64);
    }
    if (lane == 0 && w < 8) { rb[w] = s; rb[8 + w] = q; }
    __syncthreads();
    s = 0.f; q = 0.f;
    #pragma unroll
    for (int i = 0; i < 8; ++i) { s += rb[i]; q += rb[8 + i]; }
    __syncthreads();
    float mu = s * (1.f / 512.f);
    float var = q * (1.f / 512.f) - mu * mu;
    float rs = rsqrtf(var + 1e-5f);
    float y = 0.f;
    if (act) y = (v - mu) * rs * gg[c] + bt[c];
    float ss = act ? y * y : 0.f;
    #pragma unroll
    for (int m = 1; m < 64; m <<= 1) ss += __shfl_xor(ss, m, 64);
    if (lane == 0 && w < 8) rb[w] = ss;
    __syncthreads();
    ss = 0.f;
    #pragma unroll
    for (int i = 0; i < 8; ++i) ss += rb[i];
    float invn = 1.f / fmaxf(sqrtf(ss), 1e-12f);
    if (act) {
      float o = y * invn;
      outp[(size_t)r2 * 512 + c] = o;
      if (!isv) Tt[(size_t)c * 256 + r2] = o;
    }
  }
}

// ---------------- mega2: unit_sim (0..255) + logits_row (256..511), 512 thr ----------------
__global__ __launch_bounds__(512) void k_mega2(
    const float* __restrict__ vpp, const float* __restrict__ tpp,
    const float* __restrict__ lsc, float* __restrict__ simout,
    float* __restrict__ up, float* __restrict__ uc,
    const float* __restrict__ vgp, const float* __restrict__ Tt,
    float* __restrict__ logits, float* __restrict__ logitsT,
    float* __restrict__ diag, float* __restrict__ rlse) {
  __shared__ float Sp[2][64][81];
  __shared__ float lse_r[64];
  __shared__ int bestt[64];
  __shared__ float lse_c[80];
  __shared__ int bestv[80];
  __shared__ float rbuf[8];
  const int tid = threadIdx.x;
  const int w = tid >> 6, lane = tid & 63;
  const int hi = lane >> 4, lo = lane & 15;
  const float scale = fminf(expf(lsc[0]), 100.f);

  if (blockIdx.x < 256) {
    // ================= per-batch sim + mutual-NN unit loss =================
    const int b = blockIdx.x;
    const int wq = w >> 1, kg = w & 1;

    f32x4 acc[5];
    #pragma unroll
    for (int ct = 0; ct < 5; ++ct) acc[ct] = (f32x4){0.f, 0.f, 0.f, 0.f};

    const float* va = vpp + ((size_t)b * 64 + wq * 16 + lo) * 512 + kg * 256;
    const float* tbase = tpp + (size_t)b * 77 * 512 + kg * 256;
    for (int k0 = 0; k0 < 256; k0 += 32) {
      float4 f0 = *(const float4*)(va + k0 + hi * 8);
      float4 f1 = *(const float4*)(va + k0 + hi * 8 + 4);
      short8 a = {f2bf(f0.x), f2bf(f0.y), f2bf(f0.z), f2bf(f0.w),
                  f2bf(f1.x), f2bf(f1.y), f2bf(f1.z), f2bf(f1.w)};
      #pragma unroll
      for (int ct = 0; ct < 5; ++ct) {
        int rj = ct * 16 + lo;
        short8 bb = {0, 0, 0, 0, 0, 0, 0, 0};
        if (rj < 77) {
          const float* tb = tbase + (size_t)rj * 512 + k0 + hi * 8;
          float4 g0 = *(const float4*)tb;
          float4 g1 = *(const float4*)(tb + 4);
          bb = (short8){f2bf(g0.x), f2bf(g0.y), f2bf(g0.z), f2bf(g0.w),
                        f2bf(g1.x), f2bf(g1.y), f2bf(g1.z), f2bf(g1.w)};
        }
        acc[ct] = __builtin_amdgcn_mfma_f32_16x16x32_bf16(a, bb, acc[ct], 0, 0, 0);
      }
    }
    #pragma unroll
    for (int ct = 0; ct < 5; ++ct)
      #pragma unroll
      for (int r = 0; r < 4; ++r) {
        int i = wq * 16 + hi * 4 + r, j = ct * 16 + lo;
        if (j < 77) Sp[kg][i][j] = acc[ct][r];
      }
    __syncthreads();
    for (int idx = tid; idx < 64 * 77; idx += 512) {
      int i = idx / 77, j = idx - i * 77;
      float s = Sp[0][i][j] + Sp[1][i][j];
      simout[((size_t)b * 64 + i) * 77 + j] = s;
      Sp[0][i][j] = s * scale;
    }
    __syncthreads();
    if (tid < 64) {
      float mx = -1e30f; int am = 0;
      for (int t = 0; t < 77; ++t) { float x = Sp[0][tid][t]; if (x > mx) { mx = x; am = t; } }
      float se = 0.f;
      for (int t = 0; t < 77; ++t) se += expf(Sp[0][tid][t] - mx);
      lse_r[tid] = mx + logf(se); bestt[tid] = am;
    } else if (tid < 64 + 77) {
      int t = tid - 64;
      float mx = -1e30f; int am = 0;
      for (int v = 0; v < 64; ++v) { float x = Sp[0][v][t]; if (x > mx) { mx = x; am = v; } }
      float se = 0.f;
      for (int v = 0; v < 64; ++v) se += expf(Sp[0][v][t] - mx);
      lse_c[t] = mx + logf(se); bestv[t] = am;
    }
    __syncthreads();
    float c = 0.f, cnt = 0.f;
    if (tid < 64) {
      int j = bestt[tid];
      if (bestv[j] == tid) {
        float sv = Sp[0][tid][j];
        c = -((sv - lse_r[tid]) + (sv - lse_c[j]));
        cnt = 2.f;
      }
    }
    c = blk_sum_(c, rbuf, 8);
    cnt = blk_sum_(cnt, rbuf, 8);
    if (tid == 0) { up[b] = c; uc[b] = cnt; }
  } else {
    // ================= logits row (i = bid-256), tid<256 active =================
    float* vrow = &Sp[0][0][0];              // 512 floats (aliased)
    const int i = blockIdx.x - 256;
    vrow[tid] = vgp[(size_t)i * 512 + tid];  // 512 threads load 512 elems
    __syncthreads();
    float lg = -1e30f;
    if (tid < 256) {
      float s = 0.f;
      #pragma unroll 8
      for (int k = 0; k < 512; ++k)
        s += vrow[k] * Tt[(size_t)k * 256 + tid];
      lg = scale * s;
      logits[(size_t)i * 256 + tid] = lg;
      logitsT[(size_t)tid * 256 + i] = lg;
      if (tid == i) diag[i] = lg;
    }
    float mx = blk_max_(lg, rbuf, 8);
    float se = blk_sum_(tid < 256 ? expf(lg - mx) : 0.f, rbuf, 8);
    if (tid == 0) rlse[i] = mx + logf(se);
  }
}

// ---------------- logits cols: coalesced via logits^T ----------------
__global__ __launch_bounds__(256) void k_logits_col(
    const float* __restrict__ logitsT, float* __restrict__ clse) {
  __shared__ float rbuf[4];
  const int j = blockIdx.x, tid = threadIdx.x;
  float lg = logitsT[(size_t)j * 256 + tid];
  float mx = blk_max_(lg, rbuf, 4);
  float se = blk_sum_(expf(lg - mx), rbuf, 4);
  if (tid == 0) clse[j] = mx + logf(se);
}

// ---------------- final scalar losses ----------------
__global__ __launch_bounds__(256) void k_final(
    const float* __restrict__ diag, const float* __restrict__ rlse,
    const float* __restrict__ clse, const float* __restrict__ up,
    const float* __restrict__ uc, const float* __restrict__ part,
    float* __restrict__ out) {
  __shared__ float rbuf[4];
  const int tid = threadIdx.x;
  float d = diag[tid];
  float s1 = blk_sum_(d - rlse[tid], rbuf, 4);
  float s2 = blk_sum_(d - clse[tid], rbuf, 4);
  float su = blk_sum_(up[tid], rbuf, 4);
  float sc = blk_sum_(uc[tid], rbuf, 4);
  float sv = blk_sum_(part[tid], rbuf, 4);
  float st = blk_sum_(part[tid + 256], rbuf, 4);
  if (tid == 0) {
    out[0] = -(s1 * (1.f / 256.f) + s2 * (1.f / 256.f)) * 0.5f;
    out[1] = su / fmaxf(sc, 1.f);
    out[2] = (sv / (256.f * 64.f * 63.f) + st / (256.f * 77.f * 76.f)) * 0.5f;
  }
}

extern "C" void kernel_launch(void* const* d_in, const int* in_sizes, int n_in,
                              void* d_out, int out_size, void* d_ws, size_t ws_size,
                              hipStream_t stream) {
  const float* vis_units = (const float*)d_in[0];
  const float* txt_units = (const float*)d_in[1];
  const float* vis_cls = (const float*)d_in[2];
  const float* txt_cls = (const float*)d_in[3];
  const float* vW1 = (const float*)d_in[4];
  const float* vb1 = (const float*)d_in[5];
  const float* vg  = (const float*)d_in[6];
  const float* vbt = (const float*)d_in[7];
  const float* vW2 = (const float*)d_in[8];
  const float* vb2 = (const float*)d_in[9];
  const float* tW1 = (const float*)d_in[10];
  const float* tb1 = (const float*)d_in[11];
  const float* tg  = (const float*)d_in[12];
  const float* tbt = (const float*)d_in[13];
  const float* tW2 = (const float*)d_in[14];
  const float* tb2 = (const float*)d_in[15];
  const float* gvW = (const float*)d_in[16];
  const float* gvb = (const float*)d_in[17];
  const float* gvg = (const float*)d_in[18];
  const float* gvbt = (const float*)d_in[19];
  const float* gtW = (const float*)d_in[20];
  const float* gtb = (const float*)d_in[21];
  const float* gtg = (const float*)d_in[22];
  const float* gtbt = (const float*)d_in[23];
  const float* lsc = (const float*)d_in[24];

  float* out = (float*)d_out;
  char* ws = (char*)d_ws;
  short* vW1T = (short*)(ws + WS_VW1T);
  short* vW2T = (short*)(ws + WS_VW2T);
  short* tW1T = (short*)(ws + WS_TW1T);
  short* tW2T = (short*)(ws + WS_TW2T);
  short* gvWT = (short*)(ws + WS_GVWT);
  short* gtWT = (short*)(ws + WS_GTWT);
  float* logits = (float*)(ws + WS_LOG);
  float* diag = (float*)(ws + WS_DIAG);
  float* rlse = (float*)(ws + WS_RLSE);
  float* clse = (float*)(ws + WS_CLSE);
  float* up = (float*)(ws + WS_UP);
  float* uc = (float*)(ws + WS_UC);
  float* part = (float*)(ws + WS_PART);
  float* Tt = (float*)(ws + WS_TT);
  float* logitsT = (float*)(ws + WS_LOGT);

  // merged prep (weight fragment cvt + global-proj transposes)
  k_prep<<<3072, 256, 0, stream>>>(vW1, vW2, tW1, tW2, vW1T, vW2T, tW1T, tW2T,
                                   gvW, gvWT, gtW, gtWT);

  // mega: unit MLPs (+fused vis diversity) + txt diversity + global projections
  k_mega<<<1204, 1024, 0, stream>>>(
      vis_units, txt_units,
      vW1T, vb1, vg, vbt, vW2T, vb2,
      tW1T, tb1, tg, tbt, tW2T, tb2,
      out + O_VP, out + O_TP,
      vis_cls, txt_cls,
      gvWT, gvb, gvg, gvbt, gtWT, gtb, gtg, gtbt,
      out + O_VG, out + O_TG, Tt, part);

  // mega2: unit sim + logits rows (independent, co-scheduled)
  k_mega2<<<512, 512, 0, stream>>>(
      out + O_VP, out + O_TP, lsc, out + O_SM, up, uc,
      out + O_VG, Tt, logits, logitsT, diag, rlse);

  // logits cols
  k_logits_col<<<256, 256, 0, stream>>>(logitsT, clse);

  // final scalars
  k_final<<<1, 256, 0, stream>>>(diag, rlse, clse, up, uc, part, out);

  (void)in_sizes; (void)n_in; (void)out_size; (void)ws_size;
}